// Round 1
// 2072.539 us; speedup vs baseline: 1.1774x; 1.1774x over previous
//
#include <hip/hip_runtime.h>
#include <hip/hip_bf16.h>
#include <cmath>

using bf16 = __hip_bfloat16;
typedef __bf16 bfx8 __attribute__((ext_vector_type(8)));
typedef float floatx4 __attribute__((ext_vector_type(4)));

__device__ __forceinline__ float b2f(bf16 v) { return __bfloat162float(v); }

// async global->LDS, 16B per lane. LDS dest must be wave-uniform base + lane*16.
__device__ __forceinline__ void gll16(const bf16* g, short* l) {
    void* gv = (void*)g;  // drop const
    __builtin_amdgcn_global_load_lds((__attribute__((address_space(1))) void*)gv,
                                     (__attribute__((address_space(3))) void*)l,
                                     16, 0, 0);
}

// ---- dtype detection: flag=1 -> inputs are f32, flag=0 -> inputs are bf16 --
__global__ void detect_dtype(const unsigned short* x, int* flag) {
    __shared__ int cnt[256];
    int t = threadIdx.x, bad = 0;
    for (int i = t; i < 8192; i += 256) {
        unsigned short lo = x[2 * i];
        int e = (lo >> 7) & 0xFF;
        if (e == 0xFF || e >= 0xC6 || (e != 0 && e <= 0x30)) bad++;
    }
    cnt[t] = bad; __syncthreads();
    if (t == 0) { int s = 0; for (int i = 0; i < 256; i++) s += cnt[i]; *flag = (s > 819) ? 1 : 0; }
}

__device__ __forceinline__ float rd(const void* src, long i, int f) {
    return f ? ((const float*)src)[i] : b2f(((const bf16*)src)[i]);
}

// raw (flag-dtype) -> bf16 scratch
__global__ void cvt_b16(const void* __restrict__ src, bf16* __restrict__ dst,
                        long n, const int* __restrict__ flag) {
    int f = *flag;
    long i = (long)blockIdx.x * 256 + threadIdx.x;
    if (i < n) dst[i] = __float2bfloat16(rd(src, i, f));
}

// All projection weights -> bf16 Wall[12][3*768][768] : rows 0..767=Wq[h],
// 768..1535=Wk[h], 1536..2303=Wv[h]. 4 elems/thread along columns.
__global__ void cvt_wall(const void* __restrict__ q, const void* __restrict__ k,
                         const void* __restrict__ v, bf16* __restrict__ dst,
                         const int* __restrict__ flag) {
    int f = *flag;
    long i = (long)blockIdx.x * 256 + threadIdx.x;     // 27648*192 = 5,308,416
    if (i >= 5308416L) return;
    long row = i / 192;
    int c0 = (int)(i - row * 192) * 4;
    long h = row / 2304, rr = row - h * 2304;
    long s = rr / 768, r = rr - s * 768;
    const void* src = (s == 0) ? q : (s == 1) ? k : v;
    long base = h * 589824 + r * 768 + c0;
    bf16* d = dst + row * 768 + c0;
#pragma unroll
    for (int j = 0; j < 4; j++) d[j] = __float2bfloat16(rd(src, base + j, f));
}

// Wmap [197,2364] -> bf16 padded [197, 12*224], zeros in pad columns
__global__ void pad_wmap(const void* wm, bf16* wp, const int* flag) {
    int f = *flag;
    int idx = blockIdx.x * 256 + threadIdx.x;   // 197*2688
    if (idx >= 197 * 2688) return;
    int t = idx / 2688, c = idx - t * 2688;
    int h = c / 224, j = c - h * 224;
    wp[idx] = __float2bfloat16(j < 197 ? rd(wm, (long)t * 2364 + h * 197 + j, f) : 0.f);
}

// LayerNorm over D=768 -> bf16. srcraw=1: src raw flag-dtype; 0: src bf16 buf.
__global__ __launch_bounds__(256) void ln_bf(const void* __restrict__ src, int srcraw,
                                             const void* __restrict__ gw,
                                             const void* __restrict__ bw,
                                             bf16* __restrict__ dst, long row0,
                                             const int* __restrict__ flag)
{
    const int fl = *flag;
    const long gr = row0 + blockIdx.x;
    const int t = threadIdx.x;
    float v[3], s = 0.f, s2 = 0.f;
#pragma unroll
    for (int i = 0; i < 3; i++) {
        long gi = gr * 768 + t + 256 * i;
        float f0 = srcraw ? rd(src, gi, fl) : b2f(((const bf16*)src)[gi]);
        v[i] = f0; s += f0; s2 += f0 * f0;
    }
#pragma unroll
    for (int o = 32; o; o >>= 1) { s += __shfl_xor(s, o); s2 += __shfl_xor(s2, o); }
    __shared__ float a1[4], a2[4];
    if ((t & 63) == 0) { a1[t >> 6] = s; a2[t >> 6] = s2; }
    __syncthreads();
    s = a1[0] + a1[1] + a1[2] + a1[3];
    s2 = a2[0] + a2[1] + a2[2] + a2[3];
    float mu = s * (1.f / 768.f);
    float var = s2 * (1.f / 768.f) - mu * mu;
    float rstd = rsqrtf(var + 1e-5f);
#pragma unroll
    for (int i = 0; i < 3; i++) {
        int c = t + 256 * i;
        dst[(long)blockIdx.x * 768 + c] =
            __float2bfloat16((v[i] - mu) * rstd * rd(gw, c, fl) + rd(bw, c, fl));
    }
}

// softmax over 197 fp32 scores -> bf16 rows padded to 224 with zeros
__global__ __launch_bounds__(256) void softmax_rows(const float* __restrict__ sc,
                                                    bf16* __restrict__ attn, long nrows)
{
    const long row = (long)blockIdx.x * 4 + (threadIdx.x >> 6);
    if (row >= nrows) return;
    const int lane = threadIdx.x & 63;
    const float* sr = sc + row * 197;
    float v[4], mx = -1e30f;
#pragma unroll
    for (int j = 0; j < 4; j++) {
        int s = lane + j * 64;
        float f = (s < 197) ? sr[s] : -1e30f;
        v[j] = f; mx = fmaxf(mx, f);
    }
#pragma unroll
    for (int o = 32; o; o >>= 1) mx = fmaxf(mx, __shfl_xor(mx, o));
    float sum = 0.f;
#pragma unroll
    for (int j = 0; j < 4; j++) {
        int s = lane + j * 64;
        float e = (s < 197) ? __expf(v[j] - mx) : 0.f;
        v[j] = e; sum += e;
    }
#pragma unroll
    for (int o = 32; o; o >>= 1) sum += __shfl_xor(sum, o);
    float inv = 1.f / sum;
    bf16* ar = attn + row * 224;
#pragma unroll
    for (int j = 0; j < 4; j++) {
        int s = lane + j * 64;
        if (s < 224) ar[s] = __float2bfloat16((s < 197) ? v[j] * inv : 0.f);
    }
}

// ---------------------------------------------------------------------------
// MFMA C = A @ B^T (+epilogue). A:[M,lda] bf16, B:[N,ldb] bf16 (row-major).
// 128x128 tile, BK=32, 256 threads (4 waves 2x2), mfma_f32_16x16x32_bf16.
// Staging: __builtin_amdgcn_global_load_lds width=16 (async DMA, m97 pattern).
// Batched via blockIdx.z (strides sA/sB). K must be a multiple of 32.
// MODE 2: C f32 scores[bz*38809 + m*197 + n] = val
// MODE 3: C bf16 aoT[(bz*768+n)*2688 + hoff + m] = val
// MODE 4: C bf16 outS[(row0+bz*197+m)*768+n] = val + bmap(raw1)[m] + x(raw2)[gi]
// MODE 5: C bf16 [m*3072+n] = gelu(val + raw1[n])               (mlp1)
// MODE 6: d_out[(row0+m)*768+n] = val + raw1[n] + bf16 raw2[m*768+n]; dtype=flag
// MODE 7: fused qkv, N=2304. n<768: C=q (bias raw1, *scale); n<1536: C2=k
//         (bias raw2); else C3=vT[(b*768+nn)*224+t] (bias raw3). r1off=h*768.
// ---------------------------------------------------------------------------
template <int MODE>
__global__ __launch_bounds__(256) void mgemm(
    const bf16* __restrict__ Aall, const bf16* __restrict__ Ball,
    void* __restrict__ C, void* __restrict__ C2, void* __restrict__ C3,
    const void* __restrict__ raw1, long r1off, const void* __restrict__ raw2,
    const void* __restrict__ raw3,
    int M, int N, int K, int lda, int ldb, long sA, long sB,
    int hoff, long row0, float scale, const int* __restrict__ flag)
{
    __shared__ short As[4096];   // 128 rows x 32 k (bf16)
    __shared__ short Bs[4096];

    const int tid  = threadIdx.x;
    const int wave = tid >> 6, lane = tid & 63;
    const int wy = wave >> 1, wx = wave & 1;
    const int lane16 = lane & 15, kg = lane >> 4;
    const int m0 = blockIdx.y * 128, n0 = blockIdx.x * 128;
    const int bz = blockIdx.z;

    const bf16* A = Aall + (long)bz * sA;
    const bf16* B = Ball + (long)bz * sB;

    // chunk c (0..511): row = c>>2, k-chunk = (c&3)*8 ; LDS short offset = c*8
    // wave-uniform LDS dest: chunk = wave*64+lane -> byte = wave*1024 + lane*16
    const int c0 = tid, c1 = tid + 256;
    const long rA0 = min(m0 + (c0 >> 2), M - 1);
    const long rA1 = min(m0 + (c1 >> 2), M - 1);
    const long rB0 = min(n0 + (c0 >> 2), N - 1);
    const long rB1 = min(n0 + (c1 >> 2), N - 1);
    const int k0c = (c0 & 3) * 8, k1c = (c1 & 3) * 8;

    const bf16* pA0 = A + rA0 * lda + k0c;
    const bf16* pA1 = A + rA1 * lda + k1c;
    const bf16* pB0 = B + rB0 * ldb + k0c;
    const bf16* pB1 = B + rB1 * ldb + k1c;

    floatx4 acc[4][4];
#pragma unroll
    for (int i = 0; i < 4; i++)
#pragma unroll
        for (int j = 0; j < 4; j++) acc[i][j] = (floatx4){0.f, 0.f, 0.f, 0.f};

    const int aoff = (wy * 64 + lane16) * 32 + kg * 8;  // shorts
    const int boff = (wx * 64 + lane16) * 32 + kg * 8;

    for (int kt = 0; kt < K; kt += 32) {
        __syncthreads();                      // previous iteration's reads done
        gll16(pA0 + kt, As + c0 * 8);
        gll16(pA1 + kt, As + c1 * 8);
        gll16(pB0 + kt, Bs + c0 * 8);
        gll16(pB1 + kt, Bs + c1 * 8);
        __syncthreads();                      // vmcnt drained, LDS visible
        bfx8 a[4], b[4];
#pragma unroll
        for (int i = 0; i < 4; i++) a[i] = *(const bfx8*)(As + aoff + i * 512);
#pragma unroll
        for (int j = 0; j < 4; j++) b[j] = *(const bfx8*)(Bs + boff + j * 512);
#pragma unroll
        for (int i = 0; i < 4; i++)
#pragma unroll
            for (int j = 0; j < 4; j++)
                acc[i][j] = __builtin_amdgcn_mfma_f32_16x16x32_bf16(a[i], b[j], acc[i][j], 0, 0, 0);
    }

    // epilogue. C/D: col = lane&15, row = (lane>>4)*4 + r  [m89/m91 verified]
    const int fl = *flag;
    const int mbase = m0 + wy * 64 + kg * 4;
    const int nbase = n0 + wx * 64 + lane16;
#pragma unroll
    for (int i = 0; i < 4; i++) {
#pragma unroll
        for (int j = 0; j < 4; j++) {
            const int n = nbase + j * 16;
#pragma unroll
            for (int r = 0; r < 4; r++) {
                const int m = mbase + i * 16 + r;
                if (m >= M || n >= N) continue;
                float val = acc[i][j][r];
                if constexpr (MODE == 2) {
                    ((float*)C)[(long)bz * 38809 + (long)m * 197 + n] = val;
                } else if constexpr (MODE == 3) {
                    ((bf16*)C)[((long)bz * 768 + n) * 2688 + hoff + m] = __float2bfloat16(val);
                } else if constexpr (MODE == 4) {
                    long gi = (row0 + (long)bz * 197 + m) * 768 + n;
                    ((bf16*)C)[gi] =
                        __float2bfloat16(val + rd(raw1, m, fl) + rd(raw2, gi, fl));
                } else if constexpr (MODE == 5) {
                    float xv = val + rd(raw1, r1off + n, fl);
                    xv = 0.5f * xv * (1.f + erff(xv * 0.70710678f));
                    ((bf16*)C)[(long)m * 3072 + n] = __float2bfloat16(xv);
                } else if constexpr (MODE == 6) {
                    float res = val + rd(raw1, r1off + n, fl)
                              + b2f(((const bf16*)raw2)[(long)m * 768 + n]);
                    long ad = (row0 + m) * 768 + n;
                    if (fl) ((float*)C)[ad] = res;
                    else    ((bf16*)C)[ad] = __float2bfloat16(res);
                } else if constexpr (MODE == 7) {
                    if (n < 768) {
                        ((bf16*)C)[(long)m * 768 + n] =
                            __float2bfloat16((val + rd(raw1, r1off + n, fl)) * scale);
                    } else if (n < 1536) {
                        const int nn = n - 768;
                        ((bf16*)C2)[(long)m * 768 + nn] =
                            __float2bfloat16(val + rd(raw2, r1off + nn, fl));
                    } else {
                        const int nn = n - 1536;
                        const int b_ = m / 197, t = m - b_ * 197;
                        ((bf16*)C3)[((long)b_ * 768 + nn) * 224 + t] =
                            __float2bfloat16(val + rd(raw3, r1off + nn, fl));
                    }
                }
            }
        }
    }
}

extern "C" void kernel_launch(void* const* d_in, const int* in_sizes, int n_in,
                              void* d_out, int out_size, void* d_ws, size_t ws_size,
                              hipStream_t stream)
{
    const void* x    = d_in[0];
    const void* ln1g = d_in[1];
    const void* ln1b = d_in[2];
    const void* Wq   = d_in[3];
    const void* bq   = d_in[4];
    const void* Wk   = d_in[5];
    const void* bk   = d_in[6];
    const void* Wv   = d_in[7];
    const void* bv   = d_in[8];
    const void* Wmap = d_in[9];
    const void* bmap = d_in[10];
    const void* ln2g = d_in[11];
    const void* ln2b = d_in[12];
    const void* W1   = d_in[13];
    const void* b1   = d_in[14];
    const void* W2   = d_in[15];
    const void* b2   = d_in[16];
    (void)in_sizes; (void)n_in; (void)out_size;

    auto al   = [](size_t v) { return (v + 255) & ~(size_t)255; };
    auto cdiv = [](long a, long b) { return (int)((a + b - 1) / b); };

    // ---- reserved (lives across both phases) ----
    char* W = (char*)d_ws;
    size_t o = 0;
    auto take = [&](size_t bytes) -> char* { char* p = W + o; o += al(bytes); return p; };
    int*  flag  = (int*)take(256);
    bf16* outS  = (bf16*)take(6304ull * 768 * 2);    // x + msa (bf16)
    bf16* wmpad = (bf16*)take(197ull * 2688 * 2);    // Wmap padded per-head to 224
    bf16* Wall  = (bf16*)take(27648ull * 768 * 2);   // all-head fused q|k|v weights
    const size_t reservedB = o;
    char* arena = W + reservedB;

    // ---- adaptive chunk sizes ----
    auto p1need = [&](int BC) -> size_t {
        size_t b = (size_t)BC;
        return reservedB
             + 3 * al(b * 197 * 768 * 2)             // hlnC, qC, kC
             + al(b * 768 * 224 * 2)                 // vTC
             + al(b * 38809 * 4)                     // scoresC
             + al(b * 197 * 224 * 2)                 // attnC
             + al(b * 768 * 2688 * 2);               // aoTg
    };
    int BC = 1;
    { const int ch[6] = {32, 16, 8, 4, 2, 1};
      for (int i = 0; i < 6; i++) if (p1need(ch[i]) <= ws_size) { BC = ch[i]; break; } }

    auto p2need = [&](int MC) -> size_t {
        return reservedB + 2 * al(2359296ull * 2)
             + al((size_t)MC * 768 * 2) + al((size_t)MC * 3072 * 2);
    };
    int MC = 197;
    { const int ch[6] = {6304, 3152, 1576, 788, 394, 197};
      for (int i = 0; i < 6; i++) if (p2need(ch[i]) <= ws_size) { MC = ch[i]; break; } }

    // phase-1 buffers
    size_t po = 0;
    auto ptake = [&](size_t bytes) -> char* { char* p = arena + po; po += al(bytes); return p; };
    bf16*  hlnC    = (bf16*)ptake((size_t)BC * 197 * 768 * 2);
    bf16*  qC      = (bf16*)ptake((size_t)BC * 197 * 768 * 2);
    bf16*  kC      = (bf16*)ptake((size_t)BC * 197 * 768 * 2);
    bf16*  vTC     = (bf16*)ptake((size_t)BC * 768 * 224 * 2);
    float* scoresC = (float*)ptake((size_t)BC * 38809 * 4);
    bf16*  attnC   = (bf16*)ptake((size_t)BC * 197 * 224 * 2);
    bf16*  aoTg    = (bf16*)ptake((size_t)BC * 768 * 2688 * 2);
    // phase-2 buffers (alias arena; phase-1 data dead by then)
    size_t qo = 0;
    auto qtake = [&](size_t bytes) -> char* { char* p = arena + qo; qo += al(bytes); return p; };
    bf16* W1b = (bf16*)qtake(2359296ull * 2);
    bf16* W2b = (bf16*)qtake(2359296ull * 2);
    bf16* h2C = (bf16*)qtake((size_t)MC * 768 * 2);
    bf16* gC  = (bf16*)qtake((size_t)MC * 3072 * 2);

    detect_dtype<<<1, 256, 0, stream>>>((const unsigned short*)x, flag);
    pad_wmap<<<cdiv(197L * 2688, 256), 256, 0, stream>>>(Wmap, wmpad, flag);
    cvt_wall<<<cdiv(5308416L, 256), 256, 0, stream>>>(Wq, Wk, Wv, Wall, flag);

    const int Mr = BC * 197;
    const int gy = cdiv(Mr, 128);
    for (int c0 = 0; c0 < 32; c0 += BC) {
        const long row0 = (long)c0 * 197;
        ln_bf<<<Mr, 256, 0, stream>>>(x, 1, ln1g, ln1b, hlnC, row0, flag);
        for (int h = 0; h < 12; h++) {
            const bf16* Wh = Wall + (long)h * 3 * 589824;
            // fused q|k|v projection: M=Mr, N=2304, K=768
            mgemm<7><<<dim3(18, gy, 1), 256, 0, stream>>>(hlnC, Wh, qC, kC, vTC,
                bq, (long)h * 768, bk, bv,
                Mr, 2304, 768, 768, 768, 0, 0, 0, 0, 1.0f / 14.0f, flag);
            // scores[b] = q[b] @ k[b]^T : M=N=197, K=768
            mgemm<2><<<dim3(2, 2, BC), 256, 0, stream>>>(qC, kC, scoresC, nullptr, nullptr,
                nullptr, 0, nullptr, nullptr,
                197, 197, 768, 768, 768, 197L * 768, 197L * 768, 0, 0, 1.0f, flag);
            softmax_rows<<<cdiv((long)Mr, 4), 256, 0, stream>>>(scoresC, attnC, Mr);
            // ao[b] = attn[b] @ vT[b]^T : M=197, N=768, K=224 -> aoTg slice h
            mgemm<3><<<dim3(6, 2, BC), 256, 0, stream>>>(attnC, vTC, aoTg, nullptr, nullptr,
                nullptr, 0, nullptr, nullptr,
                197, 768, 224, 224, 224, 197L * 224, 768L * 224, h * 224, 0, 1.0f, flag);
        }
        // outS = Wmap_pad @ aoTg[b]^T + bmap + x : M=197, N=768, K=2688
        mgemm<4><<<dim3(6, 2, BC), 256, 0, stream>>>(wmpad, aoTg, outS, nullptr, nullptr,
            bmap, 0, x, nullptr,
            197, 768, 2688, 2688, 2688, 0, 768L * 2688, 0, row0, 1.0f, flag);
    }

    // ---- MLP phase ----
    cvt_b16<<<cdiv(2359296, 256), 256, 0, stream>>>(W1, W1b, 2359296, flag);
    cvt_b16<<<cdiv(2359296, 256), 256, 0, stream>>>(W2, W2b, 2359296, flag);
    for (int r0 = 0; r0 < 6304; r0 += MC) {
        const int gy2 = cdiv(MC, 128);
        ln_bf<<<MC, 256, 0, stream>>>(outS, 0, ln2g, ln2b, h2C, r0, flag);
        mgemm<5><<<dim3(24, gy2, 1), 256, 0, stream>>>(h2C, W1b, gC, nullptr, nullptr,
            b1, 0, nullptr, nullptr,
            MC, 3072, 768, 768, 768, 0, 0, 0, 0, 1.0f, flag);
        mgemm<6><<<dim3(6, gy2, 1), 256, 0, stream>>>(gC, W2b, d_out, nullptr, nullptr,
            b2, 0, h2C, nullptr,
            MC, 768, 3072, 3072, 3072, 0, 0, 0, r0, 1.0f, flag);
    }
}

// Round 2
// 1761.247 us; speedup vs baseline: 1.3855x; 1.1767x over previous
//
#include <hip/hip_runtime.h>
#include <hip/hip_bf16.h>
#include <cmath>

using bf16 = __hip_bfloat16;
typedef __bf16 bfx8 __attribute__((ext_vector_type(8)));
typedef float floatx4 __attribute__((ext_vector_type(4)));

__device__ __forceinline__ float b2f(bf16 v) { return __bfloat162float(v); }

// async global->LDS, 16B per lane. LDS dest must be wave-uniform base + lane*16.
__device__ __forceinline__ void gll16(const bf16* g, short* l) {
    void* gv = (void*)g;  // drop const
    __builtin_amdgcn_global_load_lds((__attribute__((address_space(1))) void*)gv,
                                     (__attribute__((address_space(3))) void*)l,
                                     16, 0, 0);
}

// ---- dtype detection: flag=1 -> inputs are f32, flag=0 -> inputs are bf16 --
__global__ void detect_dtype(const unsigned short* x, int* flag) {
    __shared__ int cnt[256];
    int t = threadIdx.x, bad = 0;
    for (int i = t; i < 8192; i += 256) {
        unsigned short lo = x[2 * i];
        int e = (lo >> 7) & 0xFF;
        if (e == 0xFF || e >= 0xC6 || (e != 0 && e <= 0x30)) bad++;
    }
    cnt[t] = bad; __syncthreads();
    if (t == 0) { int s = 0; for (int i = 0; i < 256; i++) s += cnt[i]; *flag = (s > 819) ? 1 : 0; }
}

__device__ __forceinline__ float rd(const void* src, long i, int f) {
    return f ? ((const float*)src)[i] : b2f(((const bf16*)src)[i]);
}

// raw (flag-dtype) -> bf16 scratch
__global__ void cvt_b16(const void* __restrict__ src, bf16* __restrict__ dst,
                        long n, const int* __restrict__ flag) {
    int f = *flag;
    long i = (long)blockIdx.x * 256 + threadIdx.x;
    if (i < n) dst[i] = __float2bfloat16(rd(src, i, f));
}

// All projection weights -> bf16 Wall[12][3*768][768] : rows 0..767=Wq[h],
// 768..1535=Wk[h], 1536..2303=Wv[h]. 4 elems/thread along columns.
__global__ void cvt_wall(const void* __restrict__ q, const void* __restrict__ k,
                         const void* __restrict__ v, bf16* __restrict__ dst,
                         const int* __restrict__ flag) {
    int f = *flag;
    long i = (long)blockIdx.x * 256 + threadIdx.x;     // 27648*192 = 5,308,416
    if (i >= 5308416L) return;
    long row = i / 192;
    int c0 = (int)(i - row * 192) * 4;
    long h = row / 2304, rr = row - h * 2304;
    long s = rr / 768, r = rr - s * 768;
    const void* src = (s == 0) ? q : (s == 1) ? k : v;
    long base = h * 589824 + r * 768 + c0;
    bf16* d = dst + row * 768 + c0;
#pragma unroll
    for (int j = 0; j < 4; j++) d[j] = __float2bfloat16(rd(src, base + j, f));
}

// Wmap [197,2364] -> bf16 padded [197, 12*224], zeros in pad columns
__global__ void pad_wmap(const void* wm, bf16* wp, const int* flag) {
    int f = *flag;
    int idx = blockIdx.x * 256 + threadIdx.x;   // 197*2688
    if (idx >= 197 * 2688) return;
    int t = idx / 2688, c = idx - t * 2688;
    int h = c / 224, j = c - h * 224;
    wp[idx] = __float2bfloat16(j < 197 ? rd(wm, (long)t * 2364 + h * 197 + j, f) : 0.f);
}

// LayerNorm over D=768 -> bf16. srcraw=1: src raw flag-dtype; 0: src bf16 buf.
__global__ __launch_bounds__(256) void ln_bf(const void* __restrict__ src, int srcraw,
                                             const void* __restrict__ gw,
                                             const void* __restrict__ bw,
                                             bf16* __restrict__ dst, long row0,
                                             const int* __restrict__ flag)
{
    const int fl = *flag;
    const long gr = row0 + blockIdx.x;
    const int t = threadIdx.x;
    float v[3], s = 0.f, s2 = 0.f;
#pragma unroll
    for (int i = 0; i < 3; i++) {
        long gi = gr * 768 + t + 256 * i;
        float f0 = srcraw ? rd(src, gi, fl) : b2f(((const bf16*)src)[gi]);
        v[i] = f0; s += f0; s2 += f0 * f0;
    }
#pragma unroll
    for (int o = 32; o; o >>= 1) { s += __shfl_xor(s, o); s2 += __shfl_xor(s2, o); }
    __shared__ float a1[4], a2[4];
    if ((t & 63) == 0) { a1[t >> 6] = s; a2[t >> 6] = s2; }
    __syncthreads();
    s = a1[0] + a1[1] + a1[2] + a1[3];
    s2 = a2[0] + a2[1] + a2[2] + a2[3];
    float mu = s * (1.f / 768.f);
    float var = s2 * (1.f / 768.f) - mu * mu;
    float rstd = rsqrtf(var + 1e-5f);
#pragma unroll
    for (int i = 0; i < 3; i++) {
        int c = t + 256 * i;
        dst[(long)blockIdx.x * 768 + c] =
            __float2bfloat16((v[i] - mu) * rstd * rd(gw, c, fl) + rd(bw, c, fl));
    }
}

// softmax over 197 fp32 scores -> bf16 rows padded to 224 with zeros
__global__ __launch_bounds__(256) void softmax_rows(const float* __restrict__ sc,
                                                    bf16* __restrict__ attn, long nrows)
{
    const long row = (long)blockIdx.x * 4 + (threadIdx.x >> 6);
    if (row >= nrows) return;
    const int lane = threadIdx.x & 63;
    const float* sr = sc + row * 197;
    float v[4], mx = -1e30f;
#pragma unroll
    for (int j = 0; j < 4; j++) {
        int s = lane + j * 64;
        float f = (s < 197) ? sr[s] : -1e30f;
        v[j] = f; mx = fmaxf(mx, f);
    }
#pragma unroll
    for (int o = 32; o; o >>= 1) mx = fmaxf(mx, __shfl_xor(mx, o));
    float sum = 0.f;
#pragma unroll
    for (int j = 0; j < 4; j++) {
        int s = lane + j * 64;
        float e = (s < 197) ? __expf(v[j] - mx) : 0.f;
        v[j] = e; sum += e;
    }
#pragma unroll
    for (int o = 32; o; o >>= 1) sum += __shfl_xor(sum, o);
    float inv = 1.f / sum;
    bf16* ar = attn + row * 224;
#pragma unroll
    for (int j = 0; j < 4; j++) {
        int s = lane + j * 64;
        if (s < 224) ar[s] = __float2bfloat16((s < 197) ? v[j] * inv : 0.f);
    }
}

// ---------------------------------------------------------------------------
// MFMA C = A @ B^T (+epilogue). A:[M,lda] bf16, B:[N,ldb] bf16 (row-major).
// 128x128 tile, BK=32, 256 threads (4 waves 2x2), mfma_f32_16x16x32_bf16.
// Staging: global_load_lds width=16, 2-phase double-buffer prefetch (T3 min
// recipe): issue next tile's loads BEFORE ds_read+MFMA, one barrier/step.
// Batched via blockIdx.z (strides sA/sB). K must be a multiple of 32.
// MODE 2: C f32 scores[bz*38809 + m*197 + n] = val
// MODE 3: z = hIn*BCp + b. C bf16 aoT[(b*768+n)*2688 + hoff + hIn*224 + m]
// MODE 4: C bf16 outS[(row0+bz*197+m)*768+n] = val + bmap(raw1)[m] + x(raw2)[gi]
// MODE 5: C bf16 [m*3072+n] = gelu(val + raw1[n])               (mlp1)
// MODE 6: d_out[(row0+m)*768+n] = val + raw1[n] + bf16 raw2[m*768+n]; dtype=flag
// MODE 7: fused qkv, z = head-in-group, N=2304, biases raw1/2/3 at
//         (r1off + z*768 + nn). n<768: C=q[z][m][n]*scale; n<1536: C2=k;
//         else C3=vT[z][(b*768+nn)*224+t], b=m/197.
// ---------------------------------------------------------------------------
template <int MODE>
__global__ __launch_bounds__(256) void mgemm(
    const bf16* __restrict__ Aall, const bf16* __restrict__ Ball,
    void* __restrict__ C, void* __restrict__ C2, void* __restrict__ C3,
    const void* __restrict__ raw1, long r1off, const void* __restrict__ raw2,
    const void* __restrict__ raw3,
    int M, int N, int K, int lda, int ldb, long sA, long sB,
    int hoff, int BCp, long row0, float scale, const int* __restrict__ flag)
{
    __shared__ short As[2][4096];   // 2 x (128 rows x 32 k) bf16
    __shared__ short Bs[2][4096];

    const int tid  = threadIdx.x;
    const int wave = tid >> 6, lane = tid & 63;
    const int wy = wave >> 1, wx = wave & 1;
    const int lane16 = lane & 15, kg = lane >> 4;
    const int m0 = blockIdx.y * 128, n0 = blockIdx.x * 128;
    const int bz = blockIdx.z;

    const bf16* A = Aall + (long)bz * sA;
    const bf16* B = Ball + (long)bz * sB;

    // chunk c (0..511): row = c>>2, k-chunk = (c&3)*8 ; LDS short offset = c*8
    // wave-uniform LDS dest: chunk = wave*64+lane -> byte = wave*1024 + lane*16
    const int c0 = tid, c1 = tid + 256;
    const long rA0 = min(m0 + (c0 >> 2), M - 1);
    const long rA1 = min(m0 + (c1 >> 2), M - 1);
    const long rB0 = min(n0 + (c0 >> 2), N - 1);
    const long rB1 = min(n0 + (c1 >> 2), N - 1);
    const int k0c = (c0 & 3) * 8, k1c = (c1 & 3) * 8;
    const int l0 = c0 * 8, l1 = c1 * 8;      // LDS short offsets

    const bf16* pA0 = A + rA0 * lda + k0c;
    const bf16* pA1 = A + rA1 * lda + k1c;
    const bf16* pB0 = B + rB0 * ldb + k0c;
    const bf16* pB1 = B + rB1 * ldb + k1c;

    floatx4 acc[4][4];
#pragma unroll
    for (int i = 0; i < 4; i++)
#pragma unroll
        for (int j = 0; j < 4; j++) acc[i][j] = (floatx4){0.f, 0.f, 0.f, 0.f};

    const int aoff = (wy * 64 + lane16) * 32 + kg * 8;  // shorts
    const int boff = (wx * 64 + lane16) * 32 + kg * 8;

    // prologue: stage k-tile 0 into buffer 0
    gll16(pA0, As[0] + l0);
    gll16(pA1, As[0] + l1);
    gll16(pB0, Bs[0] + l0);
    gll16(pB1, Bs[0] + l1);
    __syncthreads();                          // vmcnt drained, tile 0 ready

    int cur = 0;
    for (int kt = 32; kt < K; kt += 32) {
        const int nxt = cur ^ 1;
        // issue next tile's loads first -> latency hides under MFMA below
        gll16(pA0 + kt, As[nxt] + l0);
        gll16(pA1 + kt, As[nxt] + l1);
        gll16(pB0 + kt, Bs[nxt] + l0);
        gll16(pB1 + kt, Bs[nxt] + l1);
        bfx8 a[4], b[4];
#pragma unroll
        for (int i = 0; i < 4; i++) a[i] = *(const bfx8*)(As[cur] + aoff + i * 512);
#pragma unroll
        for (int j = 0; j < 4; j++) b[j] = *(const bfx8*)(Bs[cur] + boff + j * 512);
#pragma unroll
        for (int i = 0; i < 4; i++)
#pragma unroll
            for (int j = 0; j < 4; j++)
                acc[i][j] = __builtin_amdgcn_mfma_f32_16x16x32_bf16(a[i], b[j], acc[i][j], 0, 0, 0);
        __syncthreads();                      // next tile staged + reads done
        cur = nxt;
    }
    {   // final tile
        bfx8 a[4], b[4];
#pragma unroll
        for (int i = 0; i < 4; i++) a[i] = *(const bfx8*)(As[cur] + aoff + i * 512);
#pragma unroll
        for (int j = 0; j < 4; j++) b[j] = *(const bfx8*)(Bs[cur] + boff + j * 512);
#pragma unroll
        for (int i = 0; i < 4; i++)
#pragma unroll
            for (int j = 0; j < 4; j++)
                acc[i][j] = __builtin_amdgcn_mfma_f32_16x16x32_bf16(a[i], b[j], acc[i][j], 0, 0, 0);
    }

    // epilogue. C/D: col = lane&15, row = (lane>>4)*4 + r  [m89/m91 verified]
    const int fl = *flag;
    const int mbase = m0 + wy * 64 + kg * 4;
    const int nbase = n0 + wx * 64 + lane16;
    // mode-specific per-block constants
    int hIn = 0, bIn = 0;
    if constexpr (MODE == 3) { hIn = bz / BCp; bIn = bz - hIn * BCp; }
    long qb = 0, vb = 0, bb = 0;
    if constexpr (MODE == 7) {
        qb = (long)bz * M * 768;
        vb = (long)bz * (M / 197) * 768 * 224;
        bb = r1off + (long)bz * 768;
    }
#pragma unroll
    for (int i = 0; i < 4; i++) {
#pragma unroll
        for (int j = 0; j < 4; j++) {
            const int n = nbase + j * 16;
#pragma unroll
            for (int r = 0; r < 4; r++) {
                const int m = mbase + i * 16 + r;
                if (m >= M || n >= N) continue;
                float val = acc[i][j][r];
                if constexpr (MODE == 2) {
                    ((float*)C)[(long)bz * 38809 + (long)m * 197 + n] = val;
                } else if constexpr (MODE == 3) {
                    ((bf16*)C)[((long)bIn * 768 + n) * 2688 + hoff + hIn * 224 + m] =
                        __float2bfloat16(val);
                } else if constexpr (MODE == 4) {
                    long gi = (row0 + (long)bz * 197 + m) * 768 + n;
                    ((bf16*)C)[gi] =
                        __float2bfloat16(val + rd(raw1, m, fl) + rd(raw2, gi, fl));
                } else if constexpr (MODE == 5) {
                    float xv = val + rd(raw1, r1off + n, fl);
                    xv = 0.5f * xv * (1.f + erff(xv * 0.70710678f));
                    ((bf16*)C)[(long)m * 3072 + n] = __float2bfloat16(xv);
                } else if constexpr (MODE == 6) {
                    float res = val + rd(raw1, r1off + n, fl)
                              + b2f(((const bf16*)raw2)[(long)m * 768 + n]);
                    long ad = (row0 + m) * 768 + n;
                    if (fl) ((float*)C)[ad] = res;
                    else    ((bf16*)C)[ad] = __float2bfloat16(res);
                } else if constexpr (MODE == 7) {
                    if (n < 768) {
                        ((bf16*)C)[qb + (long)m * 768 + n] =
                            __float2bfloat16((val + rd(raw1, bb + n, fl)) * scale);
                    } else if (n < 1536) {
                        const int nn = n - 768;
                        ((bf16*)C2)[qb + (long)m * 768 + nn] =
                            __float2bfloat16(val + rd(raw2, bb + nn, fl));
                    } else {
                        const int nn = n - 1536;
                        const int b_ = m / 197, t = m - b_ * 197;
                        ((bf16*)C3)[vb + ((long)b_ * 768 + nn) * 224 + t] =
                            __float2bfloat16(val + rd(raw3, bb + nn, fl));
                    }
                }
            }
        }
    }
}

extern "C" void kernel_launch(void* const* d_in, const int* in_sizes, int n_in,
                              void* d_out, int out_size, void* d_ws, size_t ws_size,
                              hipStream_t stream)
{
    const void* x    = d_in[0];
    const void* ln1g = d_in[1];
    const void* ln1b = d_in[2];
    const void* Wq   = d_in[3];
    const void* bq   = d_in[4];
    const void* Wk   = d_in[5];
    const void* bk   = d_in[6];
    const void* Wv   = d_in[7];
    const void* bv   = d_in[8];
    const void* Wmap = d_in[9];
    const void* bmap = d_in[10];
    const void* ln2g = d_in[11];
    const void* ln2b = d_in[12];
    const void* W1   = d_in[13];
    const void* b1   = d_in[14];
    const void* W2   = d_in[15];
    const void* b2   = d_in[16];
    (void)in_sizes; (void)n_in; (void)out_size;

    auto al   = [](size_t v) { return (v + 255) & ~(size_t)255; };
    auto cdiv = [](long a, long b) { return (int)((a + b - 1) / b); };

    // ---- reserved (lives across both phases) ----
    char* W = (char*)d_ws;
    size_t o = 0;
    auto take = [&](size_t bytes) -> char* { char* p = W + o; o += al(bytes); return p; };
    int*  flag  = (int*)take(256);
    bf16* outS  = (bf16*)take(6304ull * 768 * 2);    // x + msa (bf16)
    bf16* wmpad = (bf16*)take(197ull * 2688 * 2);    // Wmap padded per-head to 224
    bf16* Wall  = (bf16*)take(27648ull * 768 * 2);   // all-head fused q|k|v weights
    const size_t reservedB = o;
    char* arena = W + reservedB;

    // ---- adaptive chunk sizes: BC batches, HG heads per group ----
    auto p1need = [&](int BCc, int HGc) -> size_t {
        size_t b = (size_t)BCc, g = (size_t)HGc;
        return reservedB
             + al(b * 197 * 768 * 2)                 // hlnC
             + 2 * al(g * b * 197 * 768 * 2)         // qC, kC
             + al(g * b * 768 * 224 * 2)             // vTC
             + al(g * b * 38809 * 4)                 // scoresC
             + al(g * b * 197 * 224 * 2)             // attnC
             + al(b * 768 * 2688 * 2);               // aoTg (all 12 heads)
    };
    int BC = 1, HG = 1;
    {   const int bs[6] = {32, 16, 8, 4, 2, 1};
        const int hs[6] = {12, 6, 4, 3, 2, 1};
        long best = -1;
        for (int i = 0; i < 6; i++)
            for (int j = 0; j < 6; j++) {
                long prod = (long)bs[i] * hs[j];
                if (p1need(bs[i], hs[j]) <= ws_size &&
                    (prod > best || (prod == best && hs[j] > HG))) {
                    best = prod; BC = bs[i]; HG = hs[j];
                }
            }
    }

    auto p2need = [&](int MCc) -> size_t {
        return reservedB + 2 * al(2359296ull * 2)
             + al((size_t)MCc * 768 * 2) + al((size_t)MCc * 3072 * 2);
    };
    int MC = 197;
    { const int ch[6] = {6304, 3152, 1576, 788, 394, 197};
      for (int i = 0; i < 6; i++) if (p2need(ch[i]) <= ws_size) { MC = ch[i]; break; } }

    // phase-1 buffers
    size_t po = 0;
    auto ptake = [&](size_t bytes) -> char* { char* p = arena + po; po += al(bytes); return p; };
    bf16*  hlnC    = (bf16*)ptake((size_t)BC * 197 * 768 * 2);
    bf16*  qC      = (bf16*)ptake((size_t)HG * BC * 197 * 768 * 2);
    bf16*  kC      = (bf16*)ptake((size_t)HG * BC * 197 * 768 * 2);
    bf16*  vTC     = (bf16*)ptake((size_t)HG * BC * 768 * 224 * 2);
    float* scoresC = (float*)ptake((size_t)HG * BC * 38809 * 4);
    bf16*  attnC   = (bf16*)ptake((size_t)HG * BC * 197 * 224 * 2);
    bf16*  aoTg    = (bf16*)ptake((size_t)BC * 768 * 2688 * 2);
    // phase-2 buffers (alias arena; phase-1 data dead by then)
    size_t qo = 0;
    auto qtake = [&](size_t bytes) -> char* { char* p = arena + qo; qo += al(bytes); return p; };
    bf16* W1b = (bf16*)qtake(2359296ull * 2);
    bf16* W2b = (bf16*)qtake(2359296ull * 2);
    bf16* h2C = (bf16*)qtake((size_t)MC * 768 * 2);
    bf16* gC  = (bf16*)qtake((size_t)MC * 3072 * 2);

    detect_dtype<<<1, 256, 0, stream>>>((const unsigned short*)x, flag);
    pad_wmap<<<cdiv(197L * 2688, 256), 256, 0, stream>>>(Wmap, wmpad, flag);
    cvt_wall<<<cdiv(5308416L, 256), 256, 0, stream>>>(Wq, Wk, Wv, Wall, flag);

    const int Mr = BC * 197;
    const int gy = cdiv(Mr, 128);
    for (int c0 = 0; c0 < 32; c0 += BC) {
        const long row0 = (long)c0 * 197;
        ln_bf<<<Mr, 256, 0, stream>>>(x, 1, ln1g, ln1b, hlnC, row0, flag);
        for (int hg = 0; hg < 12; hg += HG) {
            const bf16* Whg = Wall + (long)hg * 2304 * 768;
            // fused q|k|v projection, all heads in group: M=Mr, N=2304, K=768
            mgemm<7><<<dim3(18, gy, HG), 256, 0, stream>>>(hlnC, Whg, qC, kC, vTC,
                bq, (long)hg * 768, bk, bv,
                Mr, 2304, 768, 768, 768, 0, 2304L * 768, 0, BC, 0, 1.0f / 14.0f, flag);
            // scores[z] = q[z] @ k[z]^T : M=N=197, K=768, z = head_in_grp*BC + b
            mgemm<2><<<dim3(2, 2, HG * BC), 256, 0, stream>>>(qC, kC, scoresC,
                nullptr, nullptr, nullptr, 0, nullptr, nullptr,
                197, 197, 768, 768, 768, 197L * 768, 197L * 768, 0, BC, 0, 1.0f, flag);
            softmax_rows<<<cdiv((long)HG * Mr, 4), 256, 0, stream>>>(scoresC, attnC,
                (long)HG * Mr);
            // ao[z] = attn[z] @ vT[z]^T : M=197, N=768, K=224 -> aoTg head slice
            mgemm<3><<<dim3(6, 2, HG * BC), 256, 0, stream>>>(attnC, vTC, aoTg,
                nullptr, nullptr, nullptr, 0, nullptr, nullptr,
                197, 768, 224, 224, 224, 197L * 224, 768L * 224, hg * 224, BC, 0, 1.0f, flag);
        }
        // outS = Wmap_pad @ aoTg[b]^T + bmap + x : M=197, N=768, K=2688
        mgemm<4><<<dim3(6, 2, BC), 256, 0, stream>>>(wmpad, aoTg, outS,
            nullptr, nullptr, bmap, 0, x, nullptr,
            197, 768, 2688, 2688, 2688, 0, 768L * 2688, 0, 0, row0, 1.0f, flag);
    }

    // ---- MLP phase ----
    cvt_b16<<<cdiv(2359296, 256), 256, 0, stream>>>(W1, W1b, 2359296, flag);
    cvt_b16<<<cdiv(2359296, 256), 256, 0, stream>>>(W2, W2b, 2359296, flag);
    for (int r0 = 0; r0 < 6304; r0 += MC) {
        const int gy2 = cdiv(MC, 128);
        ln_bf<<<MC, 256, 0, stream>>>(outS, 0, ln2g, ln2b, h2C, r0, flag);
        mgemm<5><<<dim3(24, gy2, 1), 256, 0, stream>>>(h2C, W1b, gC,
            nullptr, nullptr, b1, 0, nullptr, nullptr,
            MC, 3072, 768, 768, 768, 0, 0, 0, 0, 0, 1.0f, flag);
        mgemm<6><<<dim3(6, gy2, 1), 256, 0, stream>>>(gC, W2b, d_out,
            nullptr, nullptr, b2, 0, h2C, nullptr,
            MC, 768, 3072, 3072, 3072, 0, 0, 0, 0, r0, 1.0f, flag);
    }
}

// Round 3
// 1375.993 us; speedup vs baseline: 1.7734x; 1.2800x over previous
//
#include <hip/hip_runtime.h>
#include <hip/hip_bf16.h>
#include <cmath>

using bf16 = __hip_bfloat16;
typedef __bf16 bfx8 __attribute__((ext_vector_type(8)));
typedef float floatx4 __attribute__((ext_vector_type(4)));

__device__ __forceinline__ float b2f(bf16 v) { return __bfloat162float(v); }

// async global->LDS, 16B per lane. LDS dest must be wave-uniform base + lane*16.
__device__ __forceinline__ void gll16(const bf16* g, short* l) {
    void* gv = (void*)g;  // drop const
    __builtin_amdgcn_global_load_lds((__attribute__((address_space(1))) void*)gv,
                                     (__attribute__((address_space(3))) void*)l,
                                     16, 0, 0);
}

// ---- dtype detection: flag=1 -> inputs are f32, flag=0 -> inputs are bf16 --
__global__ void detect_dtype(const unsigned short* x, int* flag) {
    __shared__ int cnt[256];
    int t = threadIdx.x, bad = 0;
    for (int i = t; i < 8192; i += 256) {
        unsigned short lo = x[2 * i];
        int e = (lo >> 7) & 0xFF;
        if (e == 0xFF || e >= 0xC6 || (e != 0 && e <= 0x30)) bad++;
    }
    cnt[t] = bad; __syncthreads();
    if (t == 0) { int s = 0; for (int i = 0; i < 256; i++) s += cnt[i]; *flag = (s > 819) ? 1 : 0; }
}

__device__ __forceinline__ float rd(const void* src, long i, int f) {
    return f ? ((const float*)src)[i] : b2f(((const bf16*)src)[i]);
}

// raw (flag-dtype) -> bf16 scratch
__global__ void cvt_b16(const void* __restrict__ src, bf16* __restrict__ dst,
                        long n, const int* __restrict__ flag) {
    int f = *flag;
    long i = (long)blockIdx.x * 256 + threadIdx.x;
    if (i < n) dst[i] = __float2bfloat16(rd(src, i, f));
}

// tiled transpose-convert: WqT[h][d][e] = bf16(Wq[h][e][d]), same for Wk.
// grid (24,24,24): z = h*2 + which, 32x32 tiles, block 256 = 32x8.
__global__ __launch_bounds__(256) void tcvt(const void* __restrict__ q,
                                            const void* __restrict__ k,
                                            bf16* __restrict__ WqT, bf16* __restrict__ WkT,
                                            const int* __restrict__ flag) {
    const int f = *flag;
    __shared__ float tl[32][33];
    const int zh = blockIdx.z >> 1, w = blockIdx.z & 1;
    const void* src = w ? k : q;
    bf16* dst = w ? WkT : WqT;
    const int e0 = blockIdx.x * 32, d0 = blockIdx.y * 32;
    const int tx = threadIdx.x & 31, ty = threadIdx.x >> 5;
    const long base = (long)zh * 589824;
#pragma unroll
    for (int i = 0; i < 32; i += 8)
        tl[ty + i][tx] = rd(src, base + (long)(e0 + ty + i) * 768 + d0 + tx, f);
    __syncthreads();
#pragma unroll
    for (int i = 0; i < 32; i += 8)
        dst[base + (long)(d0 + ty + i) * 768 + e0 + tx] = __float2bfloat16(tl[tx][ty + i]);
}

// Wv rows straight into Wcomb rows [768,1536): Wcomb[h][768+e][d] = bf16(Wv[h][e][d])
__global__ void cvt_wv(const void* __restrict__ Wv, bf16* __restrict__ Wcomb,
                       const int* __restrict__ flag) {
    int f = *flag;
    long i = (long)blockIdx.x * 256 + threadIdx.x;   // 12*589824
    if (i >= 7077888L) return;
    long h = i / 589824, r = i - h * 589824;
    Wcomb[h * 1179648 + 589824 + r] = __float2bfloat16(rd(Wv, i, f));
}

// wvec[h][d] = sum_e Wk[h][e][d] * bq[h][e] / 14    grid (3,12)
__global__ __launch_bounds__(256) void mk_wvec(const void* __restrict__ Wk,
                                               const void* __restrict__ bq,
                                               float* __restrict__ wvec,
                                               const int* __restrict__ flag) {
    int f = *flag;
    int h = blockIdx.y, d = blockIdx.x * 256 + threadIdx.x;
    long base = (long)h * 589824;
    float s = 0.f;
    for (int e = 0; e < 768; e++)
        s += rd(Wk, base + (long)e * 768 + d, f) * rd(bq, h * 768 + e, f);
    wvec[h * 768 + d] = s * (1.0f / 14.0f);
}

// vC[(h*BC + b)*197 + t] = dot(hln[b*197+t], wvec[h])   grid = BC*197 blocks
__global__ __launch_bounds__(256) void vrow(const bf16* __restrict__ hln,
                                            const float* __restrict__ wvec,
                                            float* __restrict__ vC, int BC) {
    const int gr = blockIdx.x;
    const int b = gr / 197, tt = gr - b * 197;
    const int t = threadIdx.x;
    const float h0 = b2f(hln[(long)gr * 768 + t]);
    const float h1 = b2f(hln[(long)gr * 768 + t + 256]);
    const float h2 = b2f(hln[(long)gr * 768 + t + 512]);
    __shared__ float red[4];
    for (int h = 0; h < 12; h++) {
        const float* wv = wvec + h * 768;
        float s = h0 * wv[t] + h1 * wv[t + 256] + h2 * wv[t + 512];
#pragma unroll
        for (int o = 32; o; o >>= 1) s += __shfl_xor(s, o);
        if ((t & 63) == 0) red[t >> 6] = s;
        __syncthreads();
        if (t == 0) vC[((long)h * BC + b) * 197 + tt] = red[0] + red[1] + red[2] + red[3];
        __syncthreads();
    }
}

// Wmap [197,2364] -> bf16 padded [197, 12*224], zeros in pad columns
__global__ void pad_wmap(const void* wm, bf16* wp, const int* flag) {
    int f = *flag;
    int idx = blockIdx.x * 256 + threadIdx.x;   // 197*2688
    if (idx >= 197 * 2688) return;
    int t = idx / 2688, c = idx - t * 2688;
    int h = c / 224, j = c - h * 224;
    wp[idx] = __float2bfloat16(j < 197 ? rd(wm, (long)t * 2364 + h * 197 + j, f) : 0.f);
}

// LayerNorm over D=768 -> bf16. srcraw=1: src raw flag-dtype; 0: src bf16 buf.
__global__ __launch_bounds__(256) void ln_bf(const void* __restrict__ src, int srcraw,
                                             const void* __restrict__ gw,
                                             const void* __restrict__ bw,
                                             bf16* __restrict__ dst, long row0,
                                             const int* __restrict__ flag)
{
    const int fl = *flag;
    const long gr = row0 + blockIdx.x;
    const int t = threadIdx.x;
    float v[3], s = 0.f, s2 = 0.f;
#pragma unroll
    for (int i = 0; i < 3; i++) {
        long gi = gr * 768 + t + 256 * i;
        float f0 = srcraw ? rd(src, gi, fl) : b2f(((const bf16*)src)[gi]);
        v[i] = f0; s += f0; s2 += f0 * f0;
    }
#pragma unroll
    for (int o = 32; o; o >>= 1) { s += __shfl_xor(s, o); s2 += __shfl_xor(s2, o); }
    __shared__ float a1[4], a2[4];
    if ((t & 63) == 0) { a1[t >> 6] = s; a2[t >> 6] = s2; }
    __syncthreads();
    s = a1[0] + a1[1] + a1[2] + a1[3];
    s2 = a2[0] + a2[1] + a2[2] + a2[3];
    float mu = s * (1.f / 768.f);
    float var = s2 * (1.f / 768.f) - mu * mu;
    float rstd = rsqrtf(var + 1e-5f);
#pragma unroll
    for (int i = 0; i < 3; i++) {
        int c = t + 256 * i;
        dst[(long)blockIdx.x * 768 + c] =
            __float2bfloat16((v[i] - mu) * rstd * rd(gw, c, fl) + rd(bw, c, fl));
    }
}

// softmax over 197 fp32 scores -> bf16 rows padded to 224 with zeros
__global__ __launch_bounds__(256) void softmax_rows(const float* __restrict__ sc,
                                                    bf16* __restrict__ attn, long nrows)
{
    const long row = (long)blockIdx.x * 4 + (threadIdx.x >> 6);
    if (row >= nrows) return;
    const int lane = threadIdx.x & 63;
    const float* sr = sc + row * 197;
    float v[4], mx = -1e30f;
#pragma unroll
    for (int j = 0; j < 4; j++) {
        int s = lane + j * 64;
        float f = (s < 197) ? sr[s] : -1e30f;
        v[j] = f; mx = fmaxf(mx, f);
    }
#pragma unroll
    for (int o = 32; o; o >>= 1) mx = fmaxf(mx, __shfl_xor(mx, o));
    float sum = 0.f;
#pragma unroll
    for (int j = 0; j < 4; j++) {
        int s = lane + j * 64;
        float e = (s < 197) ? __expf(v[j] - mx) : 0.f;
        v[j] = e; sum += e;
    }
#pragma unroll
    for (int o = 32; o; o >>= 1) sum += __shfl_xor(sum, o);
    float inv = 1.f / sum;
    bf16* ar = attn + row * 224;
#pragma unroll
    for (int j = 0; j < 4; j++) {
        int s = lane + j * 64;
        if (s < 224) ar[s] = __float2bfloat16((s < 197) ? v[j] * inv : 0.f);
    }
}

// reduce 4 split-K partials + bmap + x -> outS bf16.  grid = Mtot blocks
__global__ __launch_bounds__(256) void red4(const float* __restrict__ part,
                                            const void* __restrict__ bmap,
                                            const void* __restrict__ x,
                                            bf16* __restrict__ outS, long row0,
                                            int Mtot, const int* __restrict__ flag) {
    const int fl = *flag;
    const int gr = blockIdx.x;
    const int tt = gr % 197;
    const int t = threadIdx.x;
#pragma unroll
    for (int i = 0; i < 3; i++) {
        int c = t + 256 * i;
        long o = (long)gr * 768 + c;
        float s = part[o] + part[(long)Mtot * 768 + o]
                + part[2L * Mtot * 768 + o] + part[3L * Mtot * 768 + o];
        long gi = (row0 + gr) * 768 + c;
        outS[gi] = __float2bfloat16(s + rd(bmap, tt, fl) + rd(x, gi, fl));
    }
}

// reduce 4 split-K partials + b2 + h2 residual -> d_out (flag dtype). grid = Mtot
__global__ __launch_bounds__(256) void red6(const float* __restrict__ part,
                                            const void* __restrict__ b2,
                                            const bf16* __restrict__ h2,
                                            void* __restrict__ dout, long row0,
                                            int Mtot, const int* __restrict__ flag) {
    const int fl = *flag;
    const int gr = blockIdx.x;
    const int t = threadIdx.x;
#pragma unroll
    for (int i = 0; i < 3; i++) {
        int c = t + 256 * i;
        long o = (long)gr * 768 + c;
        float s = part[o] + part[(long)Mtot * 768 + o]
                + part[2L * Mtot * 768 + o] + part[3L * Mtot * 768 + o];
        float res = s + rd(b2, c, fl) + b2f(h2[o]);
        long ad = (row0 + gr) * 768 + c;
        if (fl) ((float*)dout)[ad] = res;
        else    ((bf16*)dout)[ad] = __float2bfloat16(res);
    }
}

// ---------------------------------------------------------------------------
// MFMA C = A @ B^T (+epilogue). A:[M,lda] bf16, B:[N,ldb] bf16 (row-major).
// 128x128 tile, BK=32, 256 threads (4 waves 2x2), mfma_f32_16x16x32_bf16.
// Staging: global_load_lds width=16, 2-phase double-buffer prefetch.
// MODE 0: C bf16 [bz*hoff + m*768 + n] = val*scale            (Wcomb M build)
// MODE 2: B z-index = bz%BCp. C f32 scores[bz*38809+m*197+n] = val +
//         ((f32*)raw2)[bz*197+n]                              (scores + v[s])
// MODE 3: hIn=bz/BCp,bIn=bz%BCp. C bf16 aoT[(bIn*768+n)*2688+hoff+hIn*224+m]
// MODE 5: C bf16 [m*3072+n] = gelu(val + raw1[n])             (mlp1)
// MODE 7: fused G1|vT, N=1536. n<768: C=G1[bz][m][n]=val (no bias);
//         else C3=vT[bz][(b*768+nn)*224+t] = val + bv[r1off+bz*768+nn]
// MODE 8: split-K partial. kc=bz%BCp, zb=bz/BCp; A,B += kc*K (+zb strides);
//         C f32 [(kc*hoff + zb*M + m)*768 + n] = val
// ---------------------------------------------------------------------------
template <int MODE>
__global__ __launch_bounds__(256) void mgemm(
    const bf16* __restrict__ Aall, const bf16* __restrict__ Ball,
    void* __restrict__ C, void* __restrict__ C2, void* __restrict__ C3,
    const void* __restrict__ raw1, long r1off, const void* __restrict__ raw2,
    const void* __restrict__ raw3,
    int M, int N, int K, int lda, int ldb, long sA, long sB,
    int hoff, int BCp, long row0, float scale, const int* __restrict__ flag)
{
    __shared__ short As[2][4096];   // 2 x (128 rows x 32 k) bf16
    __shared__ short Bs[2][4096];

    const int tid  = threadIdx.x;
    const int wave = tid >> 6, lane = tid & 63;
    const int wy = wave >> 1, wx = wave & 1;
    const int lane16 = lane & 15, kg = lane >> 4;
    const int m0 = blockIdx.y * 128, n0 = blockIdx.x * 128;
    const int bz = blockIdx.z;

    long aOfs, bOfs;
    if constexpr (MODE == 8) {
        const int kc = bz % BCp, zb = bz / BCp;
        aOfs = (long)zb * sA + (long)kc * K;
        bOfs = (long)zb * sB + (long)kc * K;
    } else if constexpr (MODE == 2) {
        aOfs = (long)bz * sA;
        bOfs = (long)(bz % BCp) * sB;
    } else {
        aOfs = (long)bz * sA;
        bOfs = (long)bz * sB;
    }
    const bf16* A = Aall + aOfs;
    const bf16* B = Ball + bOfs;

    // chunk c (0..511): row = c>>2, k-chunk = (c&3)*8 ; LDS short offset = c*8
    const int c0 = tid, c1 = tid + 256;
    const long rA0 = min(m0 + (c0 >> 2), M - 1);
    const long rA1 = min(m0 + (c1 >> 2), M - 1);
    const long rB0 = min(n0 + (c0 >> 2), N - 1);
    const long rB1 = min(n0 + (c1 >> 2), N - 1);
    const int k0c = (c0 & 3) * 8, k1c = (c1 & 3) * 8;
    const int l0 = c0 * 8, l1 = c1 * 8;

    const bf16* pA0 = A + rA0 * lda + k0c;
    const bf16* pA1 = A + rA1 * lda + k1c;
    const bf16* pB0 = B + rB0 * ldb + k0c;
    const bf16* pB1 = B + rB1 * ldb + k1c;

    floatx4 acc[4][4];
#pragma unroll
    for (int i = 0; i < 4; i++)
#pragma unroll
        for (int j = 0; j < 4; j++) acc[i][j] = (floatx4){0.f, 0.f, 0.f, 0.f};

    const int aoff = (wy * 64 + lane16) * 32 + kg * 8;
    const int boff = (wx * 64 + lane16) * 32 + kg * 8;

    // prologue: stage k-tile 0 into buffer 0
    gll16(pA0, As[0] + l0);
    gll16(pA1, As[0] + l1);
    gll16(pB0, Bs[0] + l0);
    gll16(pB1, Bs[0] + l1);
    __syncthreads();

    int cur = 0;
    for (int kt = 32; kt < K; kt += 32) {
        const int nxt = cur ^ 1;
        gll16(pA0 + kt, As[nxt] + l0);
        gll16(pA1 + kt, As[nxt] + l1);
        gll16(pB0 + kt, Bs[nxt] + l0);
        gll16(pB1 + kt, Bs[nxt] + l1);
        bfx8 a[4], b[4];
#pragma unroll
        for (int i = 0; i < 4; i++) a[i] = *(const bfx8*)(As[cur] + aoff + i * 512);
#pragma unroll
        for (int j = 0; j < 4; j++) b[j] = *(const bfx8*)(Bs[cur] + boff + j * 512);
#pragma unroll
        for (int i = 0; i < 4; i++)
#pragma unroll
            for (int j = 0; j < 4; j++)
                acc[i][j] = __builtin_amdgcn_mfma_f32_16x16x32_bf16(a[i], b[j], acc[i][j], 0, 0, 0);
        __syncthreads();
        cur = nxt;
    }
    {
        bfx8 a[4], b[4];
#pragma unroll
        for (int i = 0; i < 4; i++) a[i] = *(const bfx8*)(As[cur] + aoff + i * 512);
#pragma unroll
        for (int j = 0; j < 4; j++) b[j] = *(const bfx8*)(Bs[cur] + boff + j * 512);
#pragma unroll
        for (int i = 0; i < 4; i++)
#pragma unroll
            for (int j = 0; j < 4; j++)
                acc[i][j] = __builtin_amdgcn_mfma_f32_16x16x32_bf16(a[i], b[j], acc[i][j], 0, 0, 0);
    }

    // epilogue. C/D: col = lane&15, row = (lane>>4)*4 + r  [m89/m91 verified]
    const int fl = *flag;
    const int mbase = m0 + wy * 64 + kg * 4;
    const int nbase = n0 + wx * 64 + lane16;
    int hIn = 0, bIn = 0;
    if constexpr (MODE == 3) { hIn = bz / BCp; bIn = bz - hIn * BCp; }
    long qb = 0, vb = 0, bb = 0;
    if constexpr (MODE == 7) {
        qb = (long)bz * M * 768;
        vb = (long)bz * (M / 197) * 768 * 224;
        bb = r1off + (long)bz * 768;
    }
    long p8 = 0;
    if constexpr (MODE == 8) {
        const int kc = bz % BCp, zb = bz / BCp;
        p8 = (long)kc * hoff + (long)zb * M;
    }
#pragma unroll
    for (int i = 0; i < 4; i++) {
#pragma unroll
        for (int j = 0; j < 4; j++) {
            const int n = nbase + j * 16;
#pragma unroll
            for (int r = 0; r < 4; r++) {
                const int m = mbase + i * 16 + r;
                if (m >= M || n >= N) continue;
                float val = acc[i][j][r];
                if constexpr (MODE == 0) {
                    ((bf16*)C)[(long)bz * hoff + (long)m * 768 + n] =
                        __float2bfloat16(val * scale);
                } else if constexpr (MODE == 2) {
                    ((float*)C)[(long)bz * 38809 + (long)m * 197 + n] =
                        val + ((const float*)raw2)[(long)bz * 197 + n];
                } else if constexpr (MODE == 3) {
                    ((bf16*)C)[((long)bIn * 768 + n) * 2688 + hoff + hIn * 224 + m] =
                        __float2bfloat16(val);
                } else if constexpr (MODE == 5) {
                    float xv = val + rd(raw1, r1off + n, fl);
                    xv = 0.5f * xv * (1.f + erff(xv * 0.70710678f));
                    ((bf16*)C)[(long)m * 3072 + n] = __float2bfloat16(xv);
                } else if constexpr (MODE == 7) {
                    if (n < 768) {
                        ((bf16*)C)[qb + (long)m * 768 + n] = __float2bfloat16(val);
                    } else {
                        const int nn = n - 768;
                        const int b_ = m / 197, t = m - b_ * 197;
                        ((bf16*)C3)[vb + ((long)b_ * 768 + nn) * 224 + t] =
                            __float2bfloat16(val + rd(raw3, bb + nn, fl));
                    }
                } else if constexpr (MODE == 8) {
                    ((float*)C)[(p8 + m) * 768 + n] = val;
                }
            }
        }
    }
}

extern "C" void kernel_launch(void* const* d_in, const int* in_sizes, int n_in,
                              void* d_out, int out_size, void* d_ws, size_t ws_size,
                              hipStream_t stream)
{
    const void* x    = d_in[0];
    const void* ln1g = d_in[1];
    const void* ln1b = d_in[2];
    const void* Wq   = d_in[3];
    const void* bq   = d_in[4];
    const void* Wk   = d_in[5];
    const void* bk   = d_in[6];
    const void* Wv   = d_in[7];
    const void* bv   = d_in[8];
    const void* Wmap = d_in[9];
    const void* bmap = d_in[10];
    const void* ln2g = d_in[11];
    const void* ln2b = d_in[12];
    const void* W1   = d_in[13];
    const void* b1   = d_in[14];
    const void* W2   = d_in[15];
    const void* b2   = d_in[16];
    (void)in_sizes; (void)n_in; (void)out_size; (void)bk;

    auto al   = [](size_t v) { return (v + 255) & ~(size_t)255; };
    auto cdiv = [](long a, long b) { return (int)((a + b - 1) / b); };

    // ---- reserved (lives across both phases) ----
    char* W = (char*)d_ws;
    size_t o = 0;
    auto take = [&](size_t bytes) -> char* { char* p = W + o; o += al(bytes); return p; };
    int*   flag  = (int*)take(256);
    bf16*  outS  = (bf16*)take(6304ull * 768 * 2);    // x + msa (bf16)
    bf16*  wmpad = (bf16*)take(197ull * 2688 * 2);    // Wmap padded per-head to 224
    bf16*  Wcomb = (bf16*)take(12ull * 1536 * 768 * 2); // per head: [M_B | Wv] rows
    float* wvec  = (float*)take(12ull * 768 * 4);     // (Wk^T bq)/14 per head
    const size_t reservedB = o;
    char* arena = W + reservedB;

    const size_t preB = 2 * al(7077888ull * 2);       // WqT + WkT scratch

    // ---- adaptive chunk sizes: BC batches, HG heads per group ----
    auto p1need = [&](int BCc, int HGc) -> size_t {
        size_t b = (size_t)BCc, g = (size_t)HGc;
        size_t slab = al(g * b * 302592) + al(g * b * 344064) + al(g * b * 155236);
        size_t part = al(4ull * b * 605184);          // mode-4 split-K partial
        if (slab < part) slab = part;
        size_t body = al(b * 302592) + slab + al(12ull * b * 788) + al(b * 4128768ull);
        if (body < preB) body = preB;
        return reservedB + body;
    };
    int BC = 1, HG = 1;
    {   const int bs[6] = {32, 16, 8, 4, 2, 1};
        const int hs[6] = {12, 6, 4, 3, 2, 1};
        long best = -1;
        for (int i = 0; i < 6; i++)
            for (int j = 0; j < 6; j++) {
                long prod = (long)bs[i] * hs[j];
                if (p1need(bs[i], hs[j]) <= ws_size &&
                    (prod > best || (prod == best && hs[j] > HG))) {
                    best = prod; BC = bs[i]; HG = hs[j];
                }
            }
    }

    auto p2need = [&](int MCc) -> size_t {
        return reservedB + 2 * al(2359296ull * 2)
             + al((size_t)MCc * 768 * 2) + al((size_t)MCc * 3072 * 2)
             + al((size_t)MCc * 768 * 4 * 4);
    };
    int MC = 197;
    { const int ch[6] = {6304, 3152, 1576, 788, 394, 197};
      for (int i = 0; i < 6; i++) if (p2need(ch[i]) <= ws_size) { MC = ch[i]; break; } }

    // phase-1 buffers
    size_t po = 0;
    auto ptake = [&](size_t bytes) -> char* { char* p = arena + po; po += al(bytes); return p; };
    bf16*  hlnC = (bf16*)ptake((size_t)BC * 302592);
    {   // slab: G1 | vT | scores ; also hosts attn (aliases G1) and map partial
        size_t slab = al((size_t)HG * BC * 302592) + al((size_t)HG * BC * 344064)
                    + al((size_t)HG * BC * 155236);
        size_t part = al(4ull * BC * 605184);
        if (slab < part) slab = part;
        po += 0; // slab taken below
        (void)slab;
    }
    size_t slabA = al((size_t)HG * BC * 302592);
    size_t slabB = al((size_t)HG * BC * 344064);
    size_t slabC = al((size_t)HG * BC * 155236);
    size_t slabT = slabA + slabB + slabC;
    { size_t part = al(4ull * BC * 605184); if (slabT < part) slabT = part; }
    char*  slab    = ptake(slabT);
    bf16*  G1C     = (bf16*)slab;
    bf16*  vTC     = (bf16*)(slab + slabA);
    float* scoresC = (float*)(slab + slabA + slabB);
    bf16*  attnC   = (bf16*)slab;                  // aliases G1C (dead by softmax)
    float* part4   = (float*)slab;                 // aliases slab (dead by map GEMM)
    float* vC      = (float*)ptake(12ull * BC * 788);
    bf16*  aoTg    = (bf16*)ptake((size_t)BC * 4128768ull);
    // precompute scratch (aliases arena; dead before ln_bf writes)
    bf16* WqT = (bf16*)arena;
    bf16* WkT = (bf16*)(arena + al(7077888ull * 2));
    // phase-2 buffers (alias arena; phase-1 data dead by then)
    size_t qo = 0;
    auto qtake = [&](size_t bytes) -> char* { char* p = arena + qo; qo += al(bytes); return p; };
    bf16*  W1b   = (bf16*)qtake(2359296ull * 2);
    bf16*  W2b   = (bf16*)qtake(2359296ull * 2);
    bf16*  h2C   = (bf16*)qtake((size_t)MC * 768 * 2);
    bf16*  gC    = (bf16*)qtake((size_t)MC * 3072 * 2);
    float* part2 = (float*)qtake((size_t)MC * 768 * 4 * 4);

    detect_dtype<<<1, 256, 0, stream>>>((const unsigned short*)x, flag);
    pad_wmap<<<cdiv(197L * 2688, 256), 256, 0, stream>>>(Wmap, wmpad, flag);
    // precompute: WqT/WkT -> M_B = (Wk^T Wq)/14 into Wcomb rows [0,768); Wv rows; wvec
    tcvt<<<dim3(24, 24, 24), 256, 0, stream>>>(Wq, Wk, WqT, WkT, flag);
    mgemm<0><<<dim3(6, 6, 12), 256, 0, stream>>>(WkT, WqT, Wcomb, nullptr, nullptr,
        nullptr, 0, nullptr, nullptr,
        768, 768, 768, 768, 768, 589824L, 589824L, 1179648, 0, 0, 1.0f / 14.0f, flag);
    cvt_wv<<<cdiv(7077888L, 256), 256, 0, stream>>>(Wv, Wcomb, flag);
    mk_wvec<<<dim3(3, 12), 256, 0, stream>>>(Wk, bq, wvec, flag);

    const int Mr = BC * 197;
    const int gy = cdiv(Mr, 128);
    for (int c0 = 0; c0 < 32; c0 += BC) {
        const long row0 = (long)c0 * 197;
        ln_bf<<<Mr, 256, 0, stream>>>(x, 1, ln1g, ln1b, hlnC, row0, flag);
        vrow<<<Mr, 256, 0, stream>>>(hlnC, wvec, vC, BC);
        for (int hg = 0; hg < 12; hg += HG) {
            // fused G1|vT projection: M=Mr, N=1536, K=768, z = head-in-group
            mgemm<7><<<dim3(12, gy, HG), 256, 0, stream>>>(hlnC,
                Wcomb + (long)hg * 1179648, G1C, nullptr, vTC,
                nullptr, (long)hg * 768, nullptr, bv,
                Mr, 1536, 768, 768, 768, 0, 1179648L, 0, 0, 0, 1.0f, flag);
            // scores[z] = G1[z] @ hln[b]^T + v[s] : M=N=197, K=768
            mgemm<2><<<dim3(2, 2, HG * BC), 256, 0, stream>>>(G1C, hlnC, scoresC,
                nullptr, nullptr, nullptr, 0, vC + (long)hg * BC * 197, nullptr,
                197, 197, 768, 768, 768, 197L * 768, 197L * 768, 0, BC, 0, 1.0f, flag);
            softmax_rows<<<cdiv((long)HG * Mr, 4), 256, 0, stream>>>(scoresC, attnC,
                (long)HG * Mr);
            // ao[z] = attn[z] @ vT[z]^T : M=197, N=768, K=224 -> aoTg head slice
            mgemm<3><<<dim3(6, 2, HG * BC), 256, 0, stream>>>(attnC, vTC, aoTg,
                nullptr, nullptr, nullptr, 0, nullptr, nullptr,
                197, 768, 224, 224, 224, 197L * 224, 768L * 224, hg * 224, BC, 0, 1.0f, flag);
        }
        // map: split-K x4 partials, then reduce (+bmap + x) -> outS
        mgemm<8><<<dim3(6, 2, BC * 4), 256, 0, stream>>>(wmpad, aoTg, part4,
            nullptr, nullptr, nullptr, 0, nullptr, nullptr,
            197, 768, 672, 2688, 2688, 0, 768L * 2688, Mr, 4, 0, 1.0f, flag);
        red4<<<Mr, 256, 0, stream>>>(part4, bmap, x, outS, row0, Mr, flag);
    }

    // ---- MLP phase ----
    cvt_b16<<<cdiv(2359296, 256), 256, 0, stream>>>(W1, W1b, 2359296, flag);
    cvt_b16<<<cdiv(2359296, 256), 256, 0, stream>>>(W2, W2b, 2359296, flag);
    for (int r0 = 0; r0 < 6304; r0 += MC) {
        const int gy2 = cdiv(MC, 128);
        ln_bf<<<MC, 256, 0, stream>>>(outS, 0, ln2g, ln2b, h2C, r0, flag);
        mgemm<5><<<dim3(24, gy2, 1), 256, 0, stream>>>(h2C, W1b, gC,
            nullptr, nullptr, b1, 0, nullptr, nullptr,
            MC, 3072, 768, 768, 768, 0, 0, 0, 0, 0, 1.0f, flag);
        // mlp2: split-K x4 partials, then reduce (+b2 + h2 residual) -> d_out
        mgemm<8><<<dim3(6, gy2, 4), 256, 0, stream>>>(gC, W2b, part2,
            nullptr, nullptr, nullptr, 0, nullptr, nullptr,
            MC, 768, 768, 3072, 3072, 0, 0, MC, 4, 0, 1.0f, flag);
        red6<<<MC, 256, 0, stream>>>(part2, b2, h2C, d_out, r0, MC, flag);
    }
}

// Round 4
// 1266.496 us; speedup vs baseline: 1.9267x; 1.0865x over previous
//
#include <hip/hip_runtime.h>
#include <hip/hip_bf16.h>
#include <cmath>

using bf16 = __hip_bfloat16;
typedef __bf16 bfx8 __attribute__((ext_vector_type(8)));
typedef float floatx4 __attribute__((ext_vector_type(4)));

__device__ __forceinline__ float b2f(bf16 v) { return __bfloat162float(v); }

// async global->LDS, 16B per lane. LDS dest must be wave-uniform base + lane*16.
__device__ __forceinline__ void gll16(const bf16* g, short* l) {
    void* gv = (void*)g;  // drop const
    __builtin_amdgcn_global_load_lds((__attribute__((address_space(1))) void*)gv,
                                     (__attribute__((address_space(3))) void*)l,
                                     16, 0, 0);
}

// ---- dtype detection: flag=1 -> inputs are f32, flag=0 -> inputs are bf16 --
__global__ void detect_dtype(const unsigned short* x, int* flag) {
    __shared__ int cnt[256];
    int t = threadIdx.x, bad = 0;
    for (int i = t; i < 8192; i += 256) {
        unsigned short lo = x[2 * i];
        int e = (lo >> 7) & 0xFF;
        if (e == 0xFF || e >= 0xC6 || (e != 0 && e <= 0x30)) bad++;
    }
    cnt[t] = bad; __syncthreads();
    if (t == 0) { int s = 0; for (int i = 0; i < 256; i++) s += cnt[i]; *flag = (s > 819) ? 1 : 0; }
}

__device__ __forceinline__ float rd(const void* src, long i, int f) {
    return f ? ((const float*)src)[i] : b2f(((const bf16*)src)[i]);
}

// raw (flag-dtype) -> bf16 scratch
__global__ void cvt_b16(const void* __restrict__ src, bf16* __restrict__ dst,
                        long n, const int* __restrict__ flag) {
    int f = *flag;
    long i = (long)blockIdx.x * 256 + threadIdx.x;
    if (i < n) dst[i] = __float2bfloat16(rd(src, i, f));
}

// tiled transpose-convert: WqT[h][d][e] = bf16(Wq[h][e][d]), same for Wk.
// grid (24,24,24): z = h*2 + which, 32x32 tiles, block 256 = 32x8.
__global__ __launch_bounds__(256) void tcvt(const void* __restrict__ q,
                                            const void* __restrict__ k,
                                            bf16* __restrict__ WqT, bf16* __restrict__ WkT,
                                            const int* __restrict__ flag) {
    const int f = *flag;
    __shared__ float tl[32][33];
    const int zh = blockIdx.z >> 1, w = blockIdx.z & 1;
    const void* src = w ? k : q;
    bf16* dst = w ? WkT : WqT;
    const int e0 = blockIdx.x * 32, d0 = blockIdx.y * 32;
    const int tx = threadIdx.x & 31, ty = threadIdx.x >> 5;
    const long base = (long)zh * 589824;
#pragma unroll
    for (int i = 0; i < 32; i += 8)
        tl[ty + i][tx] = rd(src, base + (long)(e0 + ty + i) * 768 + d0 + tx, f);
    __syncthreads();
#pragma unroll
    for (int i = 0; i < 32; i += 8)
        dst[base + (long)(d0 + ty + i) * 768 + e0 + tx] = __float2bfloat16(tl[tx][ty + i]);
}

// Wv rows straight into Wcomb rows [768,1536): Wcomb[h][768+e][d] = bf16(Wv[h][e][d])
__global__ void cvt_wv(const void* __restrict__ Wv, bf16* __restrict__ Wcomb,
                       const int* __restrict__ flag) {
    int f = *flag;
    long i = (long)blockIdx.x * 256 + threadIdx.x;   // 12*589824
    if (i >= 7077888L) return;
    long h = i / 589824, r = i - h * 589824;
    Wcomb[h * 1179648 + 589824 + r] = __float2bfloat16(rd(Wv, i, f));
}

// wvec[h][d] = sum_e Wk[h][e][d] * bq[h][e] / 14    grid (3,12)
__global__ __launch_bounds__(256) void mk_wvec(const void* __restrict__ Wk,
                                               const void* __restrict__ bq,
                                               float* __restrict__ wvec,
                                               const int* __restrict__ flag) {
    int f = *flag;
    int h = blockIdx.y, d = blockIdx.x * 256 + threadIdx.x;
    long base = (long)h * 589824;
    float s = 0.f;
    for (int e = 0; e < 768; e++)
        s += rd(Wk, base + (long)e * 768 + d, f) * rd(bq, h * 768 + e, f);
    wvec[h * 768 + d] = s * (1.0f / 14.0f);
}

// vC[(h*BC + b)*197 + t] = dot(hln[b*197+t], wvec[h])   grid = BC*197 blocks
__global__ __launch_bounds__(256) void vrow(const bf16* __restrict__ hln,
                                            const float* __restrict__ wvec,
                                            float* __restrict__ vC, int BC) {
    const int gr = blockIdx.x;
    const int b = gr / 197, tt = gr - b * 197;
    const int t = threadIdx.x;
    const float h0 = b2f(hln[(long)gr * 768 + t]);
    const float h1 = b2f(hln[(long)gr * 768 + t + 256]);
    const float h2 = b2f(hln[(long)gr * 768 + t + 512]);
    __shared__ float red[4];
    for (int h = 0; h < 12; h++) {
        const float* wv = wvec + h * 768;
        float s = h0 * wv[t] + h1 * wv[t + 256] + h2 * wv[t + 512];
#pragma unroll
        for (int o = 32; o; o >>= 1) s += __shfl_xor(s, o);
        if ((t & 63) == 0) red[t >> 6] = s;
        __syncthreads();
        if (t == 0) vC[((long)h * BC + b) * 197 + tt] = red[0] + red[1] + red[2] + red[3];
        __syncthreads();
    }
}

// Wmap [197,2364] -> bf16 padded [197, 12*224], zeros in pad columns
__global__ void pad_wmap(const void* wm, bf16* wp, const int* flag) {
    int f = *flag;
    int idx = blockIdx.x * 256 + threadIdx.x;   // 197*2688
    if (idx >= 197 * 2688) return;
    int t = idx / 2688, c = idx - t * 2688;
    int h = c / 224, j = c - h * 224;
    wp[idx] = __float2bfloat16(j < 197 ? rd(wm, (long)t * 2364 + h * 197 + j, f) : 0.f);
}

// LayerNorm over D=768 -> bf16. srcraw=1: src raw flag-dtype; 0: src bf16 buf.
__global__ __launch_bounds__(256) void ln_bf(const void* __restrict__ src, int srcraw,
                                             const void* __restrict__ gw,
                                             const void* __restrict__ bw,
                                             bf16* __restrict__ dst, long row0,
                                             const int* __restrict__ flag)
{
    const int fl = *flag;
    const long gr = row0 + blockIdx.x;
    const int t = threadIdx.x;
    float v[3], s = 0.f, s2 = 0.f;
#pragma unroll
    for (int i = 0; i < 3; i++) {
        long gi = gr * 768 + t + 256 * i;
        float f0 = srcraw ? rd(src, gi, fl) : b2f(((const bf16*)src)[gi]);
        v[i] = f0; s += f0; s2 += f0 * f0;
    }
#pragma unroll
    for (int o = 32; o; o >>= 1) { s += __shfl_xor(s, o); s2 += __shfl_xor(s2, o); }
    __shared__ float a1[4], a2[4];
    if ((t & 63) == 0) { a1[t >> 6] = s; a2[t >> 6] = s2; }
    __syncthreads();
    s = a1[0] + a1[1] + a1[2] + a1[3];
    s2 = a2[0] + a2[1] + a2[2] + a2[3];
    float mu = s * (1.f / 768.f);
    float var = s2 * (1.f / 768.f) - mu * mu;
    float rstd = rsqrtf(var + 1e-5f);
#pragma unroll
    for (int i = 0; i < 3; i++) {
        int c = t + 256 * i;
        dst[(long)blockIdx.x * 768 + c] =
            __float2bfloat16((v[i] - mu) * rstd * rd(gw, c, fl) + rd(bw, c, fl));
    }
}

// softmax over 197 fp32 scores -> bf16 rows padded to 224 with zeros
__global__ __launch_bounds__(256) void softmax_rows(const float* __restrict__ sc,
                                                    bf16* __restrict__ attn, long nrows)
{
    const long row = (long)blockIdx.x * 4 + (threadIdx.x >> 6);
    if (row >= nrows) return;
    const int lane = threadIdx.x & 63;
    const float* sr = sc + row * 197;
    float v[4], mx = -1e30f;
#pragma unroll
    for (int j = 0; j < 4; j++) {
        int s = lane + j * 64;
        float f = (s < 197) ? sr[s] : -1e30f;
        v[j] = f; mx = fmaxf(mx, f);
    }
#pragma unroll
    for (int o = 32; o; o >>= 1) mx = fmaxf(mx, __shfl_xor(mx, o));
    float sum = 0.f;
#pragma unroll
    for (int j = 0; j < 4; j++) {
        int s = lane + j * 64;
        float e = (s < 197) ? __expf(v[j] - mx) : 0.f;
        v[j] = e; sum += e;
    }
#pragma unroll
    for (int o = 32; o; o >>= 1) sum += __shfl_xor(sum, o);
    float inv = 1.f / sum;
    bf16* ar = attn + row * 224;
#pragma unroll
    for (int j = 0; j < 4; j++) {
        int s = lane + j * 64;
        if (s < 224) ar[s] = __float2bfloat16((s < 197) ? v[j] * inv : 0.f);
    }
}

// reduce 4 split-K partials + bmap + x -> outS bf16.  grid = Mtot blocks
__global__ __launch_bounds__(256) void red4(const float* __restrict__ part,
                                            const void* __restrict__ bmap,
                                            const void* __restrict__ x,
                                            bf16* __restrict__ outS, long row0,
                                            int Mtot, const int* __restrict__ flag) {
    const int fl = *flag;
    const int gr = blockIdx.x;
    const int tt = gr % 197;
    const int t = threadIdx.x;
#pragma unroll
    for (int i = 0; i < 3; i++) {
        int c = t + 256 * i;
        long o = (long)gr * 768 + c;
        float s = part[o] + part[(long)Mtot * 768 + o]
                + part[2L * Mtot * 768 + o] + part[3L * Mtot * 768 + o];
        long gi = (row0 + gr) * 768 + c;
        outS[gi] = __float2bfloat16(s + rd(bmap, tt, fl) + rd(x, gi, fl));
    }
}

// reduce 4 split-K partials + b2 + h2 residual -> d_out (flag dtype). grid = Mtot
__global__ __launch_bounds__(256) void red6(const float* __restrict__ part,
                                            const void* __restrict__ b2,
                                            const bf16* __restrict__ h2,
                                            void* __restrict__ dout, long row0,
                                            int Mtot, const int* __restrict__ flag) {
    const int fl = *flag;
    const int gr = blockIdx.x;
    const int t = threadIdx.x;
#pragma unroll
    for (int i = 0; i < 3; i++) {
        int c = t + 256 * i;
        long o = (long)gr * 768 + c;
        float s = part[o] + part[(long)Mtot * 768 + o]
                + part[2L * Mtot * 768 + o] + part[3L * Mtot * 768 + o];
        float res = s + rd(b2, c, fl) + b2f(h2[o]);
        long ad = (row0 + gr) * 768 + c;
        if (fl) ((float*)dout)[ad] = res;
        else    ((bf16*)dout)[ad] = __float2bfloat16(res);
    }
}

// ---------------------------------------------------------------------------
// MFMA C = A @ B^T (+epilogue). A:[M,lda] bf16, B:[N,ldb] bf16 (row-major).
// 128x128 tile, BK=32, 256 threads (4 waves 2x2), mfma_f32_16x16x32_bf16.
// Staging: global_load_lds width=16, 2-phase double-buffer prefetch.
// __launch_bounds__(256,4): cap 128 regs -> 4 waves/SIMD (occupancy fix).
// MODE 0: C bf16 [bz*hoff + m*768 + n] = val*scale            (Wcomb M build)
// MODE 2: B z-index = bz%BCp. C f32 scores[bz*38809+m*197+n] = val +
//         ((f32*)raw2)[bz*197+n]                              (scores + v[s])
// MODE 3: hIn=bz/BCp,bIn=bz%BCp. C bf16 aoT[(bIn*768+n)*2688+hoff+hIn*224+m]
// MODE 5: C bf16 [m*3072+n] = gelu(val + raw1[n])             (mlp1)
// MODE 7: fused G1|vT, N=1536. n<768: C=G1[bz][m][n]=val (no bias);
//         else C3=vT[bz][(b*768+nn)*224+t] = val + bv[r1off+bz*768+nn]
// MODE 8: split-K partial. kc=bz%BCp, zb=bz/BCp; A,B += kc*K (+zb strides);
//         C f32 [(kc*hoff + zb*M + m)*768 + n] = val
// ---------------------------------------------------------------------------
template <int MODE>
__global__ __launch_bounds__(256, 4) void mgemm(
    const bf16* __restrict__ Aall, const bf16* __restrict__ Ball,
    void* __restrict__ C, void* __restrict__ C2, void* __restrict__ C3,
    const void* __restrict__ raw1, long r1off, const void* __restrict__ raw2,
    const void* __restrict__ raw3,
    int M, int N, int K, int lda, int ldb, long sA, long sB,
    int hoff, int BCp, long row0, float scale, const int* __restrict__ flag)
{
    __shared__ short As[2][4096];   // 2 x (128 rows x 32 k) bf16
    __shared__ short Bs[2][4096];

    const int tid  = threadIdx.x;
    const int wave = tid >> 6, lane = tid & 63;
    const int wy = wave >> 1, wx = wave & 1;
    const int lane16 = lane & 15, kg = lane >> 4;
    const int m0 = blockIdx.y * 128, n0 = blockIdx.x * 128;
    const int bz = blockIdx.z;

    long aOfs, bOfs;
    if constexpr (MODE == 8) {
        const int kc = bz % BCp, zb = bz / BCp;
        aOfs = (long)zb * sA + (long)kc * K;
        bOfs = (long)zb * sB + (long)kc * K;
    } else if constexpr (MODE == 2) {
        aOfs = (long)bz * sA;
        bOfs = (long)(bz % BCp) * sB;
    } else {
        aOfs = (long)bz * sA;
        bOfs = (long)bz * sB;
    }
    const bf16* A = Aall + aOfs;
    const bf16* B = Ball + bOfs;

    // chunk c (0..511): row = c>>2, k-chunk = (c&3)*8 ; LDS short offset = c*8
    const int c0 = tid, c1 = tid + 256;
    const long rA0 = min(m0 + (c0 >> 2), M - 1);
    const long rA1 = min(m0 + (c1 >> 2), M - 1);
    const long rB0 = min(n0 + (c0 >> 2), N - 1);
    const long rB1 = min(n0 + (c1 >> 2), N - 1);
    const int k0c = (c0 & 3) * 8, k1c = (c1 & 3) * 8;
    const int l0 = c0 * 8, l1 = c1 * 8;

    const bf16* pA0 = A + rA0 * lda + k0c;
    const bf16* pA1 = A + rA1 * lda + k1c;
    const bf16* pB0 = B + rB0 * ldb + k0c;
    const bf16* pB1 = B + rB1 * ldb + k1c;

    floatx4 acc[4][4];
#pragma unroll
    for (int i = 0; i < 4; i++)
#pragma unroll
        for (int j = 0; j < 4; j++) acc[i][j] = (floatx4){0.f, 0.f, 0.f, 0.f};

    const int aoff = (wy * 64 + lane16) * 32 + kg * 8;
    const int boff = (wx * 64 + lane16) * 32 + kg * 8;

    // prologue: stage k-tile 0 into buffer 0
    gll16(pA0, As[0] + l0);
    gll16(pA1, As[0] + l1);
    gll16(pB0, Bs[0] + l0);
    gll16(pB1, Bs[0] + l1);
    __syncthreads();

    int cur = 0;
    for (int kt = 32; kt < K; kt += 32) {
        const int nxt = cur ^ 1;
        gll16(pA0 + kt, As[nxt] + l0);
        gll16(pA1 + kt, As[nxt] + l1);
        gll16(pB0 + kt, Bs[nxt] + l0);
        gll16(pB1 + kt, Bs[nxt] + l1);
        bfx8 b[4];
#pragma unroll
        for (int j = 0; j < 4; j++) b[j] = *(const bfx8*)(Bs[cur] + boff + j * 512);
#pragma unroll
        for (int i = 0; i < 4; i++) {
            bfx8 a = *(const bfx8*)(As[cur] + aoff + i * 512);
#pragma unroll
            for (int j = 0; j < 4; j++)
                acc[i][j] = __builtin_amdgcn_mfma_f32_16x16x32_bf16(a, b[j], acc[i][j], 0, 0, 0);
        }
        __syncthreads();
        cur = nxt;
    }
    {
        bfx8 b[4];
#pragma unroll
        for (int j = 0; j < 4; j++) b[j] = *(const bfx8*)(Bs[cur] + boff + j * 512);
#pragma unroll
        for (int i = 0; i < 4; i++) {
            bfx8 a = *(const bfx8*)(As[cur] + aoff + i * 512);
#pragma unroll
            for (int j = 0; j < 4; j++)
                acc[i][j] = __builtin_amdgcn_mfma_f32_16x16x32_bf16(a, b[j], acc[i][j], 0, 0, 0);
        }
    }

    // epilogue. C/D: col = lane&15, row = (lane>>4)*4 + r  [m89/m91 verified]
    const int fl = *flag;
    const int mbase = m0 + wy * 64 + kg * 4;
    const int nbase = n0 + wx * 64 + lane16;
    int hIn = 0, bIn = 0;
    if constexpr (MODE == 3) { hIn = bz / BCp; bIn = bz - hIn * BCp; }
    long qb = 0, vb = 0, bb = 0;
    if constexpr (MODE == 7) {
        qb = (long)bz * M * 768;
        vb = (long)bz * (M / 197) * 768 * 224;
        bb = r1off + (long)bz * 768;
    }
    long p8 = 0;
    if constexpr (MODE == 8) {
        const int kc = bz % BCp, zb = bz / BCp;
        p8 = (long)kc * hoff + (long)zb * M;
    }
#pragma unroll
    for (int i = 0; i < 4; i++) {
#pragma unroll
        for (int j = 0; j < 4; j++) {
            const int n = nbase + j * 16;
            if constexpr (MODE == 3) {
                // packed path: 4 consecutive m -> one aligned 8B store
                const int mp = mbase + i * 16;
                if (n < N && mp + 3 < M) {
                    bf16 tmp[4];
#pragma unroll
                    for (int r = 0; r < 4; r++) tmp[r] = __float2bfloat16(acc[i][j][r]);
                    *reinterpret_cast<short4*>(
                        &((bf16*)C)[((long)bIn * 768 + n) * 2688 + hoff + hIn * 224 + mp]) =
                        *reinterpret_cast<short4*>(tmp);
                    continue;
                }
            }
#pragma unroll
            for (int r = 0; r < 4; r++) {
                const int m = mbase + i * 16 + r;
                if (m >= M || n >= N) continue;
                float val = acc[i][j][r];
                if constexpr (MODE == 0) {
                    ((bf16*)C)[(long)bz * hoff + (long)m * 768 + n] =
                        __float2bfloat16(val * scale);
                } else if constexpr (MODE == 2) {
                    ((float*)C)[(long)bz * 38809 + (long)m * 197 + n] =
                        val + ((const float*)raw2)[(long)bz * 197 + n];
                } else if constexpr (MODE == 3) {
                    ((bf16*)C)[((long)bIn * 768 + n) * 2688 + hoff + hIn * 224 + m] =
                        __float2bfloat16(val);
                } else if constexpr (MODE == 5) {
                    float xv = val + rd(raw1, r1off + n, fl);
                    xv = 0.5f * xv * (1.f + erff(xv * 0.70710678f));
                    ((bf16*)C)[(long)m * 3072 + n] = __float2bfloat16(xv);
                } else if constexpr (MODE == 7) {
                    if (n < 768) {
                        ((bf16*)C)[qb + (long)m * 768 + n] = __float2bfloat16(val);
                    } else {
                        const int nn = n - 768;
                        const int b_ = m / 197, t = m - b_ * 197;
                        ((bf16*)C3)[vb + ((long)b_ * 768 + nn) * 224 + t] =
                            __float2bfloat16(val + rd(raw3, bb + nn, fl));
                    }
                } else if constexpr (MODE == 8) {
                    ((float*)C)[(p8 + m) * 768 + n] = val;
                }
            }
        }
    }
}

extern "C" void kernel_launch(void* const* d_in, const int* in_sizes, int n_in,
                              void* d_out, int out_size, void* d_ws, size_t ws_size,
                              hipStream_t stream)
{
    const void* x    = d_in[0];
    const void* ln1g = d_in[1];
    const void* ln1b = d_in[2];
    const void* Wq   = d_in[3];
    const void* bq   = d_in[4];
    const void* Wk   = d_in[5];
    const void* bk   = d_in[6];
    const void* Wv   = d_in[7];
    const void* bv   = d_in[8];
    const void* Wmap = d_in[9];
    const void* bmap = d_in[10];
    const void* ln2g = d_in[11];
    const void* ln2b = d_in[12];
    const void* W1   = d_in[13];
    const void* b1   = d_in[14];
    const void* W2   = d_in[15];
    const void* b2   = d_in[16];
    (void)in_sizes; (void)n_in; (void)out_size; (void)bk;

    auto al   = [](size_t v) { return (v + 255) & ~(size_t)255; };
    auto cdiv = [](long a, long b) { return (int)((a + b - 1) / b); };

    // ---- reserved (lives across both phases) ----
    char* W = (char*)d_ws;
    size_t o = 0;
    auto take = [&](size_t bytes) -> char* { char* p = W + o; o += al(bytes); return p; };
    int*   flag  = (int*)take(256);
    bf16*  outS  = (bf16*)take(6304ull * 768 * 2);    // x + msa (bf16)
    bf16*  wmpad = (bf16*)take(197ull * 2688 * 2);    // Wmap padded per-head to 224
    bf16*  Wcomb = (bf16*)take(12ull * 1536 * 768 * 2); // per head: [M_B | Wv] rows
    float* wvec  = (float*)take(12ull * 768 * 4);     // (Wk^T bq)/14 per head
    const size_t reservedB = o;
    char* arena = W + reservedB;

    const size_t preB = 2 * al(7077888ull * 2);       // WqT + WkT scratch

    // ---- adaptive chunk sizes: BC batches, HG heads per group ----
    auto p1need = [&](int BCc, int HGc) -> size_t {
        size_t b = (size_t)BCc, g = (size_t)HGc;
        size_t slab = al(g * b * 302592) + al(g * b * 344064) + al(g * b * 155236);
        size_t part = al(4ull * b * 605184);          // map split-K partial
        if (slab < part) slab = part;
        size_t body = al(b * 302592) + slab + al(12ull * b * 788) + al(b * 4128768ull);
        if (body < preB) body = preB;
        return reservedB + body;
    };
    int BC = 1, HG = 1;
    {   const int bs[6] = {32, 16, 8, 4, 2, 1};
        const int hs[6] = {12, 6, 4, 3, 2, 1};
        long best = -1;
        for (int i = 0; i < 6; i++)
            for (int j = 0; j < 6; j++) {
                long prod = (long)bs[i] * hs[j];
                if (p1need(bs[i], hs[j]) <= ws_size &&
                    (prod > best || (prod == best && hs[j] > HG))) {
                    best = prod; BC = bs[i]; HG = hs[j];
                }
            }
    }

    auto p2need = [&](int MCc) -> size_t {
        return reservedB + 2 * al(2359296ull * 2)
             + al((size_t)MCc * 768 * 2) + al((size_t)MCc * 3072 * 2)
             + al((size_t)MCc * 768 * 4 * 4);
    };
    int MC = 197;
    { const int ch[6] = {6304, 3152, 1576, 788, 394, 197};
      for (int i = 0; i < 6; i++) if (p2need(ch[i]) <= ws_size) { MC = ch[i]; break; } }

    // phase-1 buffers
    size_t po = 0;
    auto ptake = [&](size_t bytes) -> char* { char* p = arena + po; po += al(bytes); return p; };
    bf16*  hlnC = (bf16*)ptake((size_t)BC * 302592);
    size_t slabA = al((size_t)HG * BC * 302592);
    size_t slabB = al((size_t)HG * BC * 344064);
    size_t slabC = al((size_t)HG * BC * 155236);
    size_t slabT = slabA + slabB + slabC;
    { size_t part = al(4ull * BC * 605184); if (slabT < part) slabT = part; }
    char*  slab    = ptake(slabT);
    bf16*  G1C     = (bf16*)slab;
    bf16*  vTC     = (bf16*)(slab + slabA);
    float* scoresC = (float*)(slab + slabA + slabB);
    bf16*  attnC   = (bf16*)slab;                  // aliases G1C (dead by softmax)
    float* part4   = (float*)slab;                 // aliases slab (dead by map GEMM)
    float* vC      = (float*)ptake(12ull * BC * 788);
    bf16*  aoTg    = (bf16*)ptake((size_t)BC * 4128768ull);
    // precompute scratch (aliases arena; dead before ln_bf writes)
    bf16* WqT = (bf16*)arena;
    bf16* WkT = (bf16*)(arena + al(7077888ull * 2));
    // phase-2 buffers (alias arena; phase-1 data dead by then)
    size_t qo = 0;
    auto qtake = [&](size_t bytes) -> char* { char* p = arena + qo; qo += al(bytes); return p; };
    bf16*  W1b   = (bf16*)qtake(2359296ull * 2);
    bf16*  W2b   = (bf16*)qtake(2359296ull * 2);
    bf16*  h2C   = (bf16*)qtake((size_t)MC * 768 * 2);
    bf16*  gC    = (bf16*)qtake((size_t)MC * 3072 * 2);
    float* part2 = (float*)qtake((size_t)MC * 768 * 4 * 4);

    detect_dtype<<<1, 256, 0, stream>>>((const unsigned short*)x, flag);
    pad_wmap<<<cdiv(197L * 2688, 256), 256, 0, stream>>>(Wmap, wmpad, flag);
    // precompute: WqT/WkT -> M_B = (Wk^T Wq)/14 into Wcomb rows [0,768); Wv rows; wvec
    tcvt<<<dim3(24, 24, 24), 256, 0, stream>>>(Wq, Wk, WqT, WkT, flag);
    mgemm<0><<<dim3(6, 6, 12), 256, 0, stream>>>(WkT, WqT, Wcomb, nullptr, nullptr,
        nullptr, 0, nullptr, nullptr,
        768, 768, 768, 768, 768, 589824L, 589824L, 1179648, 0, 0, 1.0f / 14.0f, flag);
    cvt_wv<<<cdiv(7077888L, 256), 256, 0, stream>>>(Wv, Wcomb, flag);
    mk_wvec<<<dim3(3, 12), 256, 0, stream>>>(Wk, bq, wvec, flag);

    const int Mr = BC * 197;
    const int gy = cdiv(Mr, 128);
    for (int c0 = 0; c0 < 32; c0 += BC) {
        const long row0 = (long)c0 * 197;
        ln_bf<<<Mr, 256, 0, stream>>>(x, 1, ln1g, ln1b, hlnC, row0, flag);
        vrow<<<Mr, 256, 0, stream>>>(hlnC, wvec, vC, BC);
        for (int hg = 0; hg < 12; hg += HG) {
            // fused G1|vT projection: M=Mr, N=1536, K=768, z = head-in-group
            mgemm<7><<<dim3(12, gy, HG), 256, 0, stream>>>(hlnC,
                Wcomb + (long)hg * 1179648, G1C, nullptr, vTC,
                nullptr, (long)hg * 768, nullptr, bv,
                Mr, 1536, 768, 768, 768, 0, 1179648L, 0, 0, 0, 1.0f, flag);
            // scores[z] = G1[z] @ hln[b]^T + v[s] : M=N=197, K=768
            mgemm<2><<<dim3(2, 2, HG * BC), 256, 0, stream>>>(G1C, hlnC, scoresC,
                nullptr, nullptr, nullptr, 0, vC + (long)hg * BC * 197, nullptr,
                197, 197, 768, 768, 768, 197L * 768, 197L * 768, 0, BC, 0, 1.0f, flag);
            softmax_rows<<<cdiv((long)HG * Mr, 4), 256, 0, stream>>>(scoresC, attnC,
                (long)HG * Mr);
            // ao[z] = attn[z] @ vT[z]^T : M=197, N=768, K=224 -> aoTg head slice
            mgemm<3><<<dim3(6, 2, HG * BC), 256, 0, stream>>>(attnC, vTC, aoTg,
                nullptr, nullptr, nullptr, 0, nullptr, nullptr,
                197, 768, 224, 224, 224, 197L * 224, 768L * 224, hg * 224, BC, 0, 1.0f, flag);
        }
        // map: split-K x4 partials, then reduce (+bmap + x) -> outS
        mgemm<8><<<dim3(6, 2, BC * 4), 256, 0, stream>>>(wmpad, aoTg, part4,
            nullptr, nullptr, nullptr, 0, nullptr, nullptr,
            197, 768, 672, 2688, 2688, 0, 768L * 2688, Mr, 4, 0, 1.0f, flag);
        red4<<<Mr, 256, 0, stream>>>(part4, bmap, x, outS, row0, Mr, flag);
    }

    // ---- MLP phase ----
    cvt_b16<<<cdiv(2359296, 256), 256, 0, stream>>>(W1, W1b, 2359296, flag);
    cvt_b16<<<cdiv(2359296, 256), 256, 0, stream>>>(W2, W2b, 2359296, flag);
    for (int r0 = 0; r0 < 6304; r0 += MC) {
        const int gy2 = cdiv(MC, 128);
        ln_bf<<<MC, 256, 0, stream>>>(outS, 0, ln2g, ln2b, h2C, r0, flag);
        mgemm<5><<<dim3(24, gy2, 1), 256, 0, stream>>>(h2C, W1b, gC,
            nullptr, nullptr, b1, 0, nullptr, nullptr,
            MC, 3072, 768, 768, 768, 0, 0, 0, 0, 0, 1.0f, flag);
        // mlp2: split-K x4 partials, then reduce (+b2 + h2 residual) -> d_out
        mgemm<8><<<dim3(6, gy2, 4), 256, 0, stream>>>(gC, W2b, part2,
            nullptr, nullptr, nullptr, 0, nullptr, nullptr,
            MC, 768, 768, 3072, 3072, 0, 0, MC, 4, 0, 1.0f, flag);
        red6<<<MC, 256, 0, stream>>>(part2, b2, h2C, d_out, r0, MC, flag);
    }
}